// Round 11
// baseline (755.860 us; speedup 1.0000x reference)
//
#include <hip/hip_runtime.h>
#include <hip/hip_bf16.h>

#define NN 6000
#define NPAD 6016      // 94*64
#define DF 512
#define HID 256
#define NH 8
#define NC 32
#define FTOT 2048
#define MSTR 96        // u64 words per mask row
#define NJB (NPAD / 64)
#define NJB2 (NPAD / 32)
#define L2E 1.4426950408889634f

using short8 = __attribute__((ext_vector_type(8))) short;
using f32x16 = __attribute__((ext_vector_type(16))) float;
using f32x4  = __attribute__((ext_vector_type(4))) float;

__device__ __forceinline__ unsigned short f2bf(float f) {
    unsigned int u = __float_as_uint(f);
    return (unsigned short)((u + 0x7fffu + ((u >> 16) & 1u)) >> 16);
}
__device__ __forceinline__ float bf2f(unsigned short s) {
    return __uint_as_float(((unsigned int)s) << 16);
}
// async global->LDS, 16B per lane
__device__ __forceinline__ void gl16(const void* g, void* l) {
    __builtin_amdgcn_global_load_lds(
        (const __attribute__((address_space(1))) unsigned int*)g,
        (__attribute__((address_space(3))) unsigned int*)l, 16, 0, 0);
}

// ---------------- prep kernels (verified r3/r4) ----------------

__global__ void pack_bits(const int* __restrict__ adj, unsigned char* __restrict__ maskb) {
    int row = blockIdx.y;
    int b = blockIdx.x * 256 + threadIdx.x;     // byte index 0..767
    if (b >= 768) return;
    int j0 = b * 8;
    unsigned int v = 0;
    if (j0 + 7 < NN) {
        const int4* p = (const int4*)(adj + (size_t)row * NN + j0);
        int4 a = p[0], c = p[1];
        v = (unsigned)((a.x>0) | ((a.y>0)<<1) | ((a.z>0)<<2) | ((a.w>0)<<3)
          | ((c.x>0)<<4) | ((c.y>0)<<5) | ((c.z>0)<<6) | ((c.w>0)<<7));
    }
    maskb[(size_t)row * 768 + b] = (unsigned char)v;
}

__global__ void cast_x4(const float* __restrict__ x, unsigned short* __restrict__ xb, int n4) {
    int i = blockIdx.x * 256 + threadIdx.x;
    if (i >= n4) return;
    float4 v = ((const float4*)x)[i];
    unsigned long long pk = (unsigned long long)f2bf(v.x)
        | ((unsigned long long)f2bf(v.y) << 16)
        | ((unsigned long long)f2bf(v.z) << 32)
        | ((unsigned long long)f2bf(v.w) << 48);
    ((unsigned long long*)xb)[i] = pk;
}

__global__ void wt_pack(const float* __restrict__ W0, unsigned short* __restrict__ Wt) {
    int fp = blockIdx.x;                 // h*256+f
    int h = fp >> 8, f = fp & 255;
    for (int k = threadIdx.x; k < DF; k += 256)
        Wt[(size_t)fp * DF + k] = f2bf(W0[(((size_t)h * DF + k) << 8) | f]);
}

__global__ void wct_pack(const float* __restrict__ Wc, unsigned short* __restrict__ Wct) {
    int c = blockIdx.x;
    for (int k = threadIdx.x; k < FTOT; k += 256)
        Wct[(size_t)c * FTOT + k] = f2bf(Wc[(size_t)k * NC + c]);
}

// ---------------- GEMM1 (verified r3): Ht[f][i] = sum_k X[i][k] W[k][f] ----------------
__global__ __launch_bounds__(256, 2) void gemm_h(const unsigned short* __restrict__ A,
                                                 const unsigned short* __restrict__ B,
                                                 unsigned short* __restrict__ Ht) {
    __shared__ __align__(16) unsigned short As[128 * 64];
    __shared__ __align__(16) unsigned short Bs[128 * 64];
    const int w = threadIdx.x >> 6, l = threadIdx.x & 63;
    const int lrow = l & 31, kh = l >> 5;
    const int wm = w >> 1, wn = w & 1;
    const int mbase = blockIdx.x * 128, nbase = blockIdx.y * 128;
    const int srcc = (l & 7) ^ (l >> 3);
    f32x16 acc[2][2];
#pragma unroll
    for (int i = 0; i < 2; ++i)
#pragma unroll
        for (int j = 0; j < 2; ++j) acc[i][j] = (f32x16)0.0f;

#pragma unroll 1
    for (int kb = 0; kb < DF / 64; ++kb) {
        __syncthreads();
#pragma unroll
        for (int q = 0; q < 4; ++q) {
            int c = q * 4 + w;
            int r = c * 8 + (l >> 3);
            int arow = mbase + r; if (arow > NN - 1) arow = NN - 1;
            gl16(A + (size_t)arow * DF + kb * 64 + srcc * 8, (char*)As + c * 1024);
            gl16(B + (size_t)(nbase + r) * DF + kb * 64 + srcc * 8, (char*)Bs + c * 1024);
        }
        __syncthreads();
#pragma unroll
        for (int kk = 0; kk < 4; ++kk) {
            short8 av[2], bv[2];
#pragma unroll
            for (int mt = 0; mt < 2; ++mt) {
                int r = wm * 64 + mt * 32 + lrow;
                av[mt] = *(const short8*)((const char*)As + r * 128 + ((((kk << 1) | kh) ^ (r & 7)) << 4));
            }
#pragma unroll
            for (int ft = 0; ft < 2; ++ft) {
                int r = wn * 64 + ft * 32 + lrow;
                bv[ft] = *(const short8*)((const char*)Bs + r * 128 + ((((kk << 1) | kh) ^ (r & 7)) << 4));
            }
#pragma unroll
            for (int mt = 0; mt < 2; ++mt)
#pragma unroll
                for (int ft = 0; ft < 2; ++ft)
                    acc[mt][ft] = __builtin_amdgcn_mfma_f32_32x32x16_bf16(av[mt], bv[ft], acc[mt][ft], 0, 0, 0);
        }
    }
#pragma unroll
    for (int mt = 0; mt < 2; ++mt)
#pragma unroll
        for (int ft = 0; ft < 2; ++ft) {
            size_t n = nbase + wn * 64 + ft * 32 + lrow;
#pragma unroll
            for (int g = 0; g < 4; ++g) {
                int m0 = mbase + wm * 64 + mt * 32 + (g << 3) + (kh << 2);
                unsigned long long pk =
                    (unsigned long long)f2bf(acc[mt][ft][g * 4 + 0]) |
                    ((unsigned long long)f2bf(acc[mt][ft][g * 4 + 1]) << 16) |
                    ((unsigned long long)f2bf(acc[mt][ft][g * 4 + 2]) << 32) |
                    ((unsigned long long)f2bf(acc[mt][ft][g * 4 + 3]) << 48);
                *(unsigned long long*)(Ht + n * NPAD + m0) = pk;
            }
        }
}

// ---------------- f1/f2, pre-scaled by log2e (verified r6) ----------------
__global__ void f12_kern(const unsigned short* __restrict__ Ht, const float* __restrict__ a1,
                         const float* __restrict__ a2, float* __restrict__ f1, float* __restrict__ f2,
                         int fdim) {
    int h = blockIdx.y;
    int i = blockIdx.x * 256 + threadIdx.x;
    if (i >= NPAD) return;
    float s1 = 0.f, s2 = 0.f;
    const unsigned short* base = Ht + (size_t)h * fdim * NPAD + i;
    for (int f = 0; f < fdim; ++f) {
        float v = bf2f(base[(size_t)f * NPAD]);
        s1 = fmaf(v, a1[h * fdim + f], s1);
        s2 = fmaf(v, a2[h * fdim + f], s2);
    }
    f1[(size_t)h * NPAD + i] = s1 * L2E;
    f2[(size_t)h * NPAD + i] = s2 * L2E;
}

// per-head global max -> RA/RB (verified r5/r6)
__global__ void rarb_kern(const float* __restrict__ f1all, const float* __restrict__ f2all,
                          float* __restrict__ RA, float* __restrict__ RB) {
    int h = blockIdx.x;
    __shared__ float red[8];
    const float* f2h = f2all + (size_t)h * NPAD;
    float m = -3.0e38f;
    for (int i = threadIdx.x; i < NN; i += 256) m = fmaxf(m, f2h[i]);
    for (int off = 32; off; off >>= 1) m = fmaxf(m, __shfl_xor(m, off));
    if ((threadIdx.x & 63) == 0) red[threadIdx.x >> 6] = m;
    __syncthreads();
    if (threadIdx.x == 0)
        red[4] = fmaxf(fmaxf(red[0], red[1]), fmaxf(red[2], red[3]));
    __syncthreads();
    float Mh = red[4];
    for (int i = threadIdx.x; i < NPAD; i += 256) {
        float F1 = (i < NN) ? f1all[(size_t)h * NPAD + i] : 0.f;
        float t2 = F1 + Mh;
        float Mi = fmaxf(t2, 0.2f * t2);
        RA[(size_t)h * NPAD + i] = F1 - Mi;
        RB[(size_t)h * NPAD + i] = 0.2f * F1 - Mi;
    }
}

// ---------------- main attention v8: no P duplication (row x j wave split), J=32 paired tiles ----------------
// grid 752: h = bid&7 (head->XCD pin), rowblk = bid>>3 (64 rows). 4 waves: rowhalf = w&1, jhalf = w>>1.
// Tile: [128 LDS rows][128B]: row r = {Ht[f=r], Ht[f=r+128]} x 32 j-cols; 16 KB; triple-buffered (48 KB).
// Loop = r8-verified: STAGE(t+1) -> vmcnt(4) -> s_barrier -> compute(t). Each wave computes P for its
// own (rowhalf, jhalf) partition ONCE; partial acc/asum merged through LDS at the end.
__global__ __launch_bounds__(256) void attn_main(
    const unsigned short* __restrict__ Ht,
    const unsigned long long* __restrict__ mask,
    const float* __restrict__ RA, const float* __restrict__ RB,
    const float* __restrict__ F2,
    unsigned short* __restrict__ x2)
{
    __shared__ __align__(16) unsigned short htile[3 * 128 * 64];   // 48 KB
    const int bid = blockIdx.x;
    const int h = bid & 7;
    const int rowbase = (bid >> 3) * 64;
    const int w = threadIdx.x >> 6, l = threadIdx.x & 63;
    const int lrow = l & 31, kh = l >> 5;
    const int rowhalf = w & 1, jhalf = w >> 1;
    const int myrow = rowbase + rowhalf * 32 + lrow;
    const bool act = myrow < NN;
    const int rowc = act ? myrow : NN - 1;
    const unsigned short* Hh = Ht + (size_t)h * HID * NPAD;
    const float* F2h = F2 + (size_t)h * NPAD;
    const float ra = RA[(size_t)h * NPAD + rowc], rb = RB[(size_t)h * NPAD + rowc];
    // staging source map: chunk rows r=c*8+(l>>3); stored seg (l&7) holds logical seg sc=(l&7)^(r&7)
    const int sc = (l & 7) ^ ((l >> 3) & 7);
    const int fofs = (sc >= 4) ? 128 : 0;
    const int joff = (sc & 3) * 8;
    const short8 ones = { (short)0x3F80, (short)0x3F80, (short)0x3F80, (short)0x3F80,
                          (short)0x3F80, (short)0x3F80, (short)0x3F80, (short)0x3F80 };
    f32x16 acc[8];
    f32x16 asum = (f32x16)0.0f;
#pragma unroll
    for (int i = 0; i < 8; ++i) acc[i] = (f32x16)0.0f;

    auto STAGE = [&](int buf, int jb) {
#pragma unroll
        for (int q = 0; q < 4; ++q) {
            int c = q * 4 + w;                       // chunk 0..15
            int f = c * 8 + (l >> 3) + fofs;         // feature row
            gl16(Hh + (size_t)f * NPAD + jb * 32 + joff, (char*)htile + buf * 16384 + c * 1024);
        }
    };

    STAGE(0, 0);
#pragma unroll 1
    for (int jb = 0; jb < NJB2; ++jb) {
        if (jb + 1 < NJB2) STAGE((jb + 1) % 3, jb + 1);
        asm volatile("s_waitcnt vmcnt(4)" ::: "memory");
        __builtin_amdgcn_sched_barrier(0);
        __builtin_amdgcn_s_barrier();
        __builtin_amdgcn_sched_barrier(0);
        const char* tb = (const char*)htile + (jb % 3) * 16384;
        unsigned int mw = ((const unsigned int*)(mask + (size_t)rowc * MSTR))[jb];
        unsigned int mbyte = (mw >> (jhalf * 16 + kh * 8)) & 0xffu;
        int j0 = jb * 32 + jhalf * 16 + kh * 8;
        f32x4 fa0 = *(const f32x4*)(F2h + j0);
        f32x4 fa1 = *(const f32x4*)(F2h + j0 + 4);
        float p[8];
#pragma unroll
        for (int e = 0; e < 8; ++e) {
            float fe = (e < 4) ? fa0[e & 3] : fa1[e & 3];
            float pe = exp2f(fmaxf(ra + fe, rb + 0.2f * fe));
            p[e] = (mbyte & (1u << e)) ? pe : 0.f;
        }
        union { unsigned int u[4]; short8 s8; } cv;
#pragma unroll
        for (int q = 0; q < 4; ++q)
            cv.u[q] = __builtin_amdgcn_perm(__float_as_uint(p[2 * q + 1]),
                                            __float_as_uint(p[2 * q]), 0x07060302u);
        __builtin_amdgcn_s_setprio(1);
        asum = __builtin_amdgcn_mfma_f32_32x32x16_bf16(cv.s8, ones, asum, 0, 0, 0);
#pragma unroll
        for (int ft = 0; ft < 8; ++ft) {
            int fr = ft * 32 + lrow;
            int rr_ = fr & 127;
            int seg = ((fr >> 7) << 2) | (jhalf * 2 + kh);
            short8 bfrag = *(const short8*)(tb + rr_ * 128 + (((seg ^ (rr_ & 7))) << 4));
            acc[ft] = __builtin_amdgcn_mfma_f32_32x32x16_bf16(cv.s8, bfrag, acc[ft], 0, 0, 0);
        }
        __builtin_amdgcn_s_setprio(0);
    }

    // ---- merge jhalf partials via LDS (tile dead) ----
    float* fb = (float*)htile;
    const int lbase = l * 16;
    __syncthreads();
    if (jhalf == 1) {                                   // phase A write: asum + acc[0..3]
        int base = rowhalf * 5 * 1024;
#pragma unroll
        for (int t = 0; t < 16; ++t) fb[base + lbase + t] = asum[t];
#pragma unroll
        for (int k = 0; k < 4; ++k)
#pragma unroll
            for (int t = 0; t < 16; ++t) fb[base + (k + 1) * 1024 + lbase + t] = acc[k][t];
    }
    __syncthreads();
    if (jhalf == 0) {
        int base = rowhalf * 5 * 1024;
#pragma unroll
        for (int t = 0; t < 16; ++t) asum[t] += fb[base + lbase + t];
#pragma unroll
        for (int k = 0; k < 4; ++k)
#pragma unroll
            for (int t = 0; t < 16; ++t) acc[k][t] += fb[base + (k + 1) * 1024 + lbase + t];
    }
    __syncthreads();
    if (jhalf == 1) {                                   // phase B write: acc[4..7]
        int base = rowhalf * 4 * 1024;
#pragma unroll
        for (int k = 0; k < 4; ++k)
#pragma unroll
            for (int t = 0; t < 16; ++t) fb[base + k * 1024 + lbase + t] = acc[k + 4][t];
    }
    __syncthreads();
    if (jhalf == 0) {
        int base = rowhalf * 4 * 1024;
#pragma unroll
        for (int k = 0; k < 4; ++k)
#pragma unroll
            for (int t = 0; t < 16; ++t) acc[k + 4][t] += fb[base + k * 1024 + lbase + t];

        float dinv[16];
#pragma unroll
        for (int t = 0; t < 16; ++t)
            dinv[t] = (asum[t] > 0.f) ? (1.0f / asum[t]) : 0.f;
#pragma unroll
        for (int ft = 0; ft < 8; ++ft)
#pragma unroll
            for (int g = 0; g < 4; ++g)
#pragma unroll
                for (int rr = 0; rr < 4; ++rr) {
                    int grow = rowbase + rowhalf * 32 + (g << 3) + (kh << 2) + rr;
                    if (grow < NN) {
                        float v = acc[ft][g * 4 + rr] * dinv[g * 4 + rr];
                        v = (v > 0.f) ? v : (__expf(v) - 1.f);
                        x2[(size_t)grow * FTOT + h * HID + ft * 32 + lrow] = f2bf(v);
                    }
                }
    }
}

// ---------------- GEMM2: split-K x8 -> f32 partials (verified r5) ----------------
__global__ __launch_bounds__(256, 2) void gemm_hc(const unsigned short* __restrict__ A,
                                                  const unsigned short* __restrict__ B,
                                                  float* __restrict__ pk) {
    int w = threadIdx.x >> 6, l = threadIdx.x & 63;
    int lrow = l & 31, kh = l >> 5;
    int q = blockIdx.y;
    int nbase = blockIdx.x * 128 + w * 32;
    int brow = nbase + lrow; if (brow > NN - 1) brow = NN - 1;
    f32x16 acc = (f32x16)0.0f;
    const short8* ap = (const short8*)(A + (size_t)lrow * FTOT + q * 256 + kh * 8);
    const short8* bp = (const short8*)(B + (size_t)brow * FTOT + q * 256 + kh * 8);
#pragma unroll
    for (int kk = 0; kk < 16; ++kk) {
        short8 af = ap[kk * 2];
        short8 bf = bp[kk * 2];
        acc = __builtin_amdgcn_mfma_f32_32x32x16_bf16(af, bf, acc, 0, 0, 0);
    }
    int i = nbase + lrow;
#pragma unroll
    for (int g = 0; g < 4; ++g) {
        int c0 = (g << 3) + (kh << 2);
#pragma unroll
        for (int r = 0; r < 4; ++r)
            pk[((size_t)q * NC + c0 + r) * NPAD + i] = acc[g * 4 + r];
    }
}

__global__ void merge_hc(const float* __restrict__ pk, unsigned short* __restrict__ hct) {
    int i = blockIdx.x * 256 + threadIdx.x;
    int c = blockIdx.y;
    if (i >= NPAD) return;
    float s = 0.f;
#pragma unroll
    for (int q = 0; q < 8; ++q) s += pk[((size_t)q * NC + c) * NPAD + i];
    hct[(size_t)c * NPAD + i] = f2bf(s);
}

// ---------------- classifier attention (verified r7/r8): barrier-free, j-split 4, ones dsum ----------------
__global__ __launch_bounds__(256) void cls_part(
    const unsigned short* __restrict__ hctb,
    const unsigned long long* __restrict__ mask,
    const float* __restrict__ RAc, const float* __restrict__ RBc,
    const float* __restrict__ F2c,
    float* __restrict__ pacc, float* __restrict__ pdsum)
{
    const int w = threadIdx.x >> 6, l = threadIdx.x & 63;
    const int lrow = l & 31, kh = l >> 5;
    const int q = blockIdx.y;
    const int rowbase = blockIdx.x * 128;
    const int myrow = rowbase + w * 32 + lrow;
    const bool act = myrow < NN;
    float ra = RAc[myrow], rb = RBc[myrow];
    const int JB0 = q * 24, JB1 = (JB0 + 24 < NJB) ? JB0 + 24 : NJB;
    const short8 ones = { (short)0x3F80, (short)0x3F80, (short)0x3F80, (short)0x3F80,
                          (short)0x3F80, (short)0x3F80, (short)0x3F80, (short)0x3F80 };
    f32x16 acc = (f32x16)0.0f;
    f32x16 asum = (f32x16)0.0f;

#pragma unroll 1
    for (int jb = JB0; jb < JB1; ++jb) {
        unsigned long long mword = act ? mask[(size_t)myrow * MSTR + jb] : 0ull;
#pragma unroll
        for (int kk = 0; kk < 4; ++kk) {
            short8 bfrag = *(const short8*)(hctb + (size_t)lrow * NPAD + jb * 64 + (kk * 2 + kh) * 8);
            unsigned int mbyte = (unsigned int)((mword >> (kk * 16 + kh * 8)) & 0xffull);
            int j0 = jb * 64 + kk * 16 + kh * 8;
            f32x4 fa0 = *(const f32x4*)(F2c + j0);
            f32x4 fa1 = *(const f32x4*)(F2c + j0 + 4);
            float p[8];
#pragma unroll
            for (int e = 0; e < 8; ++e) {
                float fe = (e < 4) ? fa0[e & 3] : fa1[e & 3];
                float pe = exp2f(fmaxf(ra + fe, rb + 0.2f * fe));
                p[e] = (mbyte & (1u << e)) ? pe : 0.f;
            }
            union { unsigned int u[4]; short8 s8; } cv;
#pragma unroll
            for (int t = 0; t < 4; ++t)
                cv.u[t] = __builtin_amdgcn_perm(__float_as_uint(p[2 * t + 1]),
                                                __float_as_uint(p[2 * t]), 0x07060302u);
            asum = __builtin_amdgcn_mfma_f32_32x32x16_bf16(cv.s8, ones, asum, 0, 0, 0);
            acc = __builtin_amdgcn_mfma_f32_32x32x16_bf16(cv.s8, bfrag, acc, 0, 0, 0);
        }
    }
#pragma unroll
    for (int g = 0; g < 4; ++g)
#pragma unroll
        for (int rr = 0; rr < 4; ++rr) {
            int i = rowbase + w * 32 + (g << 3) + (kh << 2) + rr;
            pacc[((size_t)q * NPAD + i) * NC + lrow] = acc[g * 4 + rr];
            if (lrow == 0) pdsum[(size_t)q * NPAD + i] = asum[g * 4 + rr];
        }
}

__global__ void cls_merge(const float* __restrict__ pacc, const float* __restrict__ pdsum,
                          float* __restrict__ outp) {
    int i = blockIdx.x * 8 + (threadIdx.x >> 5);
    int c = threadIdx.x & 31;
    if (i >= NN) return;
    float num = 0.f, den = 0.f;
#pragma unroll
    for (int q = 0; q < 4; ++q) {
        num += pacc[((size_t)q * NPAD + i) * NC + c];
        den += pdsum[(size_t)q * NPAD + i];
    }
    outp[(size_t)i * NC + c] = (den > 0.f) ? num / den : 0.f;
}

// ---------------- launcher ----------------
extern "C" void kernel_launch(void* const* d_in, const int* in_sizes, int n_in,
                              void* d_out, int out_size, void* d_ws, size_t ws_size,
                              hipStream_t stream) {
    const float* features = (const float*)d_in[0];
    const int*   adj      = (const int*)d_in[1];
    const float* W0       = (const float*)d_in[2];
    const float* a10      = (const float*)d_in[3];
    const float* a20      = (const float*)d_in[4];
    const float* Wc       = (const float*)d_in[5];
    const float* a1c      = (const float*)d_in[6];
    const float* a2c      = (const float*)d_in[7];
    float* out = (float*)d_out;

    char* p = (char*)d_ws;
    auto alloc = [&](size_t bytes) { char* r = p; p += (bytes + 255) & ~(size_t)255; return r; };
    unsigned long long* mask = (unsigned long long*)alloc((size_t)NN * MSTR * 8);
    unsigned short* Xbf = (unsigned short*)alloc((size_t)NN * DF * 2);
    unsigned short* Wt  = (unsigned short*)alloc((size_t)FTOT * DF * 2);
    unsigned short* Ht  = (unsigned short*)alloc((size_t)FTOT * NPAD * 2);
    unsigned short* x2  = (unsigned short*)alloc((size_t)NN * FTOT * 2);
    unsigned short* Wct = (unsigned short*)alloc((size_t)NC * FTOT * 2);
    unsigned short* hct = (unsigned short*)alloc((size_t)NC * NPAD * 2);
    float* f1  = (float*)alloc((size_t)NH * NPAD * 4);
    float* f2  = (float*)alloc((size_t)NH * NPAD * 4);
    float* RA  = (float*)alloc((size_t)NH * NPAD * 4);
    float* RB  = (float*)alloc((size_t)NH * NPAD * 4);
    float* f1c  = (float*)alloc((size_t)NPAD * 4);
    float* f2c  = (float*)alloc((size_t)NPAD * 4);
    float* RAc  = (float*)alloc((size_t)NPAD * 4);
    float* RBc  = (float*)alloc((size_t)NPAD * 4);
    // overlays on dead Xbf+Wt (8.26 MB): pkhc 6.16 MB (gemm_hc), then pacc 3.08 MB + pdsum 96 KB (cls)
    float* pkhc  = (float*)Xbf;
    float* pacc  = (float*)Xbf;
    float* pdsum = pacc + (size_t)4 * NPAD * NC;

    pack_bits<<<dim3(3, NN), 256, 0, stream>>>(adj, (unsigned char*)mask);
    cast_x4<<<(NN * DF / 4 + 255) / 256, 256, 0, stream>>>(features, Xbf, NN * DF / 4);
    wt_pack<<<FTOT, 256, 0, stream>>>(W0, Wt);
    wct_pack<<<NC, 256, 0, stream>>>(Wc, Wct);

    gemm_h<<<dim3(NPAD / 128, FTOT / 128), 256, 0, stream>>>(Xbf, Wt, Ht);
    f12_kern<<<dim3((NPAD + 255) / 256, NH), 256, 0, stream>>>(Ht, a10, a20, f1, f2, HID);
    rarb_kern<<<NH, 256, 0, stream>>>(f1, f2, RA, RB);

    attn_main<<<dim3(94 * NH), 256, 0, stream>>>(Ht, mask, RA, RB, f2, x2);

    gemm_hc<<<dim3(NPAD / 128, 8), 256, 0, stream>>>(Wct, x2, pkhc);
    merge_hc<<<dim3((NPAD + 255) / 256, NC), 256, 0, stream>>>(pkhc, hct);
    f12_kern<<<dim3((NPAD + 255) / 256, 1), 256, 0, stream>>>(hct, a1c, a2c, f1c, f2c, NC);
    rarb_kern<<<1, 256, 0, stream>>>(f1c, f2c, RAc, RBc);

    cls_part<<<dim3(47, 4), 256, 0, stream>>>(hct, mask, RAc, RBc, f2c, pacc, pdsum);
    cls_merge<<<750, 256, 0, stream>>>(pacc, pdsum, out);
}

// Round 12
// 663.580 us; speedup vs baseline: 1.1391x; 1.1391x over previous
//
#include <hip/hip_runtime.h>
#include <hip/hip_bf16.h>

#define NN 6000
#define NPAD 6016      // 94*64
#define DF 512
#define HID 256
#define NH 8
#define NC 32
#define FTOT 2048
#define MSTR 96        // u64 words per mask row
#define NJB (NPAD / 64)
#define L2E 1.4426950408889634f

using short8 = __attribute__((ext_vector_type(8))) short;
using f32x16 = __attribute__((ext_vector_type(16))) float;
using f32x4  = __attribute__((ext_vector_type(4))) float;

__device__ __forceinline__ unsigned short f2bf(float f) {
    unsigned int u = __float_as_uint(f);
    return (unsigned short)((u + 0x7fffu + ((u >> 16) & 1u)) >> 16);
}
__device__ __forceinline__ float bf2f(unsigned short s) {
    return __uint_as_float(((unsigned int)s) << 16);
}
// async global->LDS, 16B per lane
__device__ __forceinline__ void gl16(const void* g, void* l) {
    __builtin_amdgcn_global_load_lds(
        (const __attribute__((address_space(1))) unsigned int*)g,
        (__attribute__((address_space(3))) unsigned int*)l, 16, 0, 0);
}

// ---------------- prep kernels (verified r3/r4) ----------------

__global__ void pack_bits(const int* __restrict__ adj, unsigned char* __restrict__ maskb) {
    int row = blockIdx.y;
    int b = blockIdx.x * 256 + threadIdx.x;     // byte index 0..767
    if (b >= 768) return;
    int j0 = b * 8;
    unsigned int v = 0;
    if (j0 + 7 < NN) {
        const int4* p = (const int4*)(adj + (size_t)row * NN + j0);
        int4 a = p[0], c = p[1];
        v = (unsigned)((a.x>0) | ((a.y>0)<<1) | ((a.z>0)<<2) | ((a.w>0)<<3)
          | ((c.x>0)<<4) | ((c.y>0)<<5) | ((c.z>0)<<6) | ((c.w>0)<<7));
    }
    maskb[(size_t)row * 768 + b] = (unsigned char)v;
}

__global__ void cast_x4(const float* __restrict__ x, unsigned short* __restrict__ xb, int n4) {
    int i = blockIdx.x * 256 + threadIdx.x;
    if (i >= n4) return;
    float4 v = ((const float4*)x)[i];
    unsigned long long pk = (unsigned long long)f2bf(v.x)
        | ((unsigned long long)f2bf(v.y) << 16)
        | ((unsigned long long)f2bf(v.z) << 32)
        | ((unsigned long long)f2bf(v.w) << 48);
    ((unsigned long long*)xb)[i] = pk;
}

__global__ void wt_pack(const float* __restrict__ W0, unsigned short* __restrict__ Wt) {
    int fp = blockIdx.x;                 // h*256+f
    int h = fp >> 8, f = fp & 255;
    for (int k = threadIdx.x; k < DF; k += 256)
        Wt[(size_t)fp * DF + k] = f2bf(W0[(((size_t)h * DF + k) << 8) | f]);
}

__global__ void wct_pack(const float* __restrict__ Wc, unsigned short* __restrict__ Wct) {
    int c = blockIdx.x;
    for (int k = threadIdx.x; k < FTOT; k += 256)
        Wct[(size_t)c * FTOT + k] = f2bf(Wc[(size_t)k * NC + c]);
}

// ---------------- GEMM1 (verified r3): Ht[f][i] = sum_k X[i][k] W[k][f] ----------------
__global__ __launch_bounds__(256, 2) void gemm_h(const unsigned short* __restrict__ A,
                                                 const unsigned short* __restrict__ B,
                                                 unsigned short* __restrict__ Ht) {
    __shared__ __align__(16) unsigned short As[128 * 64];
    __shared__ __align__(16) unsigned short Bs[128 * 64];
    const int w = threadIdx.x >> 6, l = threadIdx.x & 63;
    const int lrow = l & 31, kh = l >> 5;
    const int wm = w >> 1, wn = w & 1;
    const int mbase = blockIdx.x * 128, nbase = blockIdx.y * 128;
    const int srcc = (l & 7) ^ (l >> 3);
    f32x16 acc[2][2];
#pragma unroll
    for (int i = 0; i < 2; ++i)
#pragma unroll
        for (int j = 0; j < 2; ++j) acc[i][j] = (f32x16)0.0f;

#pragma unroll 1
    for (int kb = 0; kb < DF / 64; ++kb) {
        __syncthreads();
#pragma unroll
        for (int q = 0; q < 4; ++q) {
            int c = q * 4 + w;
            int r = c * 8 + (l >> 3);
            int arow = mbase + r; if (arow > NN - 1) arow = NN - 1;
            gl16(A + (size_t)arow * DF + kb * 64 + srcc * 8, (char*)As + c * 1024);
            gl16(B + (size_t)(nbase + r) * DF + kb * 64 + srcc * 8, (char*)Bs + c * 1024);
        }
        __syncthreads();
#pragma unroll
        for (int kk = 0; kk < 4; ++kk) {
            short8 av[2], bv[2];
#pragma unroll
            for (int mt = 0; mt < 2; ++mt) {
                int r = wm * 64 + mt * 32 + lrow;
                av[mt] = *(const short8*)((const char*)As + r * 128 + ((((kk << 1) | kh) ^ (r & 7)) << 4));
            }
#pragma unroll
            for (int ft = 0; ft < 2; ++ft) {
                int r = wn * 64 + ft * 32 + lrow;
                bv[ft] = *(const short8*)((const char*)Bs + r * 128 + ((((kk << 1) | kh) ^ (r & 7)) << 4));
            }
#pragma unroll
            for (int mt = 0; mt < 2; ++mt)
#pragma unroll
                for (int ft = 0; ft < 2; ++ft)
                    acc[mt][ft] = __builtin_amdgcn_mfma_f32_32x32x16_bf16(av[mt], bv[ft], acc[mt][ft], 0, 0, 0);
        }
    }
#pragma unroll
    for (int mt = 0; mt < 2; ++mt)
#pragma unroll
        for (int ft = 0; ft < 2; ++ft) {
            size_t n = nbase + wn * 64 + ft * 32 + lrow;
#pragma unroll
            for (int g = 0; g < 4; ++g) {
                int m0 = mbase + wm * 64 + mt * 32 + (g << 3) + (kh << 2);
                unsigned long long pk =
                    (unsigned long long)f2bf(acc[mt][ft][g * 4 + 0]) |
                    ((unsigned long long)f2bf(acc[mt][ft][g * 4 + 1]) << 16) |
                    ((unsigned long long)f2bf(acc[mt][ft][g * 4 + 2]) << 32) |
                    ((unsigned long long)f2bf(acc[mt][ft][g * 4 + 3]) << 48);
                *(unsigned long long*)(Ht + n * NPAD + m0) = pk;
            }
        }
}

// ---------------- f1/f2, pre-scaled by log2e (verified r6) ----------------
__global__ void f12_kern(const unsigned short* __restrict__ Ht, const float* __restrict__ a1,
                         const float* __restrict__ a2, float* __restrict__ f1, float* __restrict__ f2,
                         int fdim) {
    int h = blockIdx.y;
    int i = blockIdx.x * 256 + threadIdx.x;
    if (i >= NPAD) return;
    float s1 = 0.f, s2 = 0.f;
    const unsigned short* base = Ht + (size_t)h * fdim * NPAD + i;
    for (int f = 0; f < fdim; ++f) {
        float v = bf2f(base[(size_t)f * NPAD]);
        s1 = fmaf(v, a1[h * fdim + f], s1);
        s2 = fmaf(v, a2[h * fdim + f], s2);
    }
    f1[(size_t)h * NPAD + i] = s1 * L2E;
    f2[(size_t)h * NPAD + i] = s2 * L2E;
}

// per-head global max -> RA/RB (verified r5/r6)
__global__ void rarb_kern(const float* __restrict__ f1all, const float* __restrict__ f2all,
                          float* __restrict__ RA, float* __restrict__ RB) {
    int h = blockIdx.x;
    __shared__ float red[8];
    const float* f2h = f2all + (size_t)h * NPAD;
    float m = -3.0e38f;
    for (int i = threadIdx.x; i < NN; i += 256) m = fmaxf(m, f2h[i]);
    for (int off = 32; off; off >>= 1) m = fmaxf(m, __shfl_xor(m, off));
    if ((threadIdx.x & 63) == 0) red[threadIdx.x >> 6] = m;
    __syncthreads();
    if (threadIdx.x == 0)
        red[4] = fmaxf(fmaxf(red[0], red[1]), fmaxf(red[2], red[3]));
    __syncthreads();
    float Mh = red[4];
    for (int i = threadIdx.x; i < NPAD; i += 256) {
        float F1 = (i < NN) ? f1all[(size_t)h * NPAD + i] : 0.f;
        float t2 = F1 + Mh;
        float Mi = fmaxf(t2, 0.2f * t2);
        RA[(size_t)h * NPAD + i] = F1 - Mi;
        RB[(size_t)h * NPAD + i] = 0.2f * F1 - Mi;
    }
}

// F2b = 0.2 * f2 (r4-verified pattern; trades 8 fma/kk for 2 loads — VALU is the bottleneck)
__global__ void prep_f2b(const float* __restrict__ f2, float* __restrict__ F2b, int n) {
    int i = blockIdx.x * 256 + threadIdx.x;
    if (i < n) F2b[i] = 0.2f * f2[i];
}

// ---------------- main attention v9: r8 loop, 6-wave blocks (192 rows), stager split ----------------
// grid 512 (= exactly 2 blocks/CU): h = bid&7 (head->XCD pin), fh = (bid>>3)&1, rowblk = bid>>4.
// 6 waves x 32 rows = 192 rows. Waves 0-3 stage (4 chunks each -> vmcnt(4) exact, r8-verified);
// waves 4-5 compute-only (vmcnt(0) trivially satisfied: in-order VMEM retirement + consumed F2 loads).
// Triple buffer 48 KB; 2 blocks x 48 = 96 <= 128 KB pool -> 12 waves/CU.
__global__ __launch_bounds__(384, 3) void attn_main(
    const unsigned short* __restrict__ Ht,
    const unsigned long long* __restrict__ mask,
    const float* __restrict__ RA, const float* __restrict__ RB,
    const float* __restrict__ F2, const float* __restrict__ F2b,
    unsigned short* __restrict__ x2)
{
    __shared__ __align__(16) unsigned short htile[3 * 128 * 64];   // 48 KB, swizzled [128][64] x3
    const int bid = blockIdx.x;
    const int h = bid & 7;
    const int fh = (bid >> 3) & 1;
    const int rowbase = (bid >> 4) * 192;
    const int w = threadIdx.x >> 6, l = threadIdx.x & 63;
    const int lrow = l & 31, kh = l >> 5;
    const int myrow = rowbase + w * 32 + lrow;
    const bool act = myrow < NN;
    const int rowc = act ? myrow : NN - 1;          // clamped for loads; stores guarded
    const unsigned short* Hh = Ht + ((size_t)h * HID + fh * 128) * NPAD;
    const float* F2h = F2 + (size_t)h * NPAD;
    const float* F2bh = F2b + (size_t)h * NPAD;
    const float ra = RA[(size_t)h * NPAD + rowc], rb = RB[(size_t)h * NPAD + rowc];
    const int srcc = (l & 7) ^ (l >> 3);
    const short8 ones = { (short)0x3F80, (short)0x3F80, (short)0x3F80, (short)0x3F80,
                          (short)0x3F80, (short)0x3F80, (short)0x3F80, (short)0x3F80 };
    f32x16 acc[4];
    f32x16 asum = (f32x16)0.0f;
#pragma unroll
    for (int i = 0; i < 4; ++i) acc[i] = (f32x16)0.0f;

    auto STAGE = [&](int buf, int jb) {
#pragma unroll
        for (int q = 0; q < 4; ++q) {
            int c = q * 4 + w;                   // chunk 0..15 (stagers w=0..3 only)
            int f = c * 8 + (l >> 3);            // tile row 0..127
            gl16(Hh + (size_t)f * NPAD + jb * 64 + srcc * 8, (char*)htile + buf * 16384 + c * 1024);
        }
    };

    if (w < 4) STAGE(0, 0);
#pragma unroll 1
    for (int jb = 0; jb < NJB; ++jb) {
        if (w < 4) {
            if (jb + 1 < NJB) STAGE((jb + 1) % 3, jb + 1);   // depth-1 prefetch
            asm volatile("s_waitcnt vmcnt(4)" ::: "memory"); // own S(jb) retired; S(jb+1) in flight
        } else {
            asm volatile("s_waitcnt vmcnt(0)" ::: "memory"); // no staging loads outstanding
        }
        __builtin_amdgcn_sched_barrier(0);
        __builtin_amdgcn_s_barrier();                        // publish tile jb (non-draining for stagers)
        __builtin_amdgcn_sched_barrier(0);
        const char* tb = (const char*)htile + (jb % 3) * 16384;
        unsigned long long mw = mask[(size_t)rowc * MSTR + jb];
#pragma unroll
        for (int kk = 0; kk < 4; ++kk) {
            unsigned int mbyte = (unsigned int)((mw >> (kk * 16 + kh * 8)) & 0xffull);
            int j0 = jb * 64 + kk * 16 + kh * 8;
            f32x4 fa0 = *(const f32x4*)(F2h + j0);
            f32x4 fa1 = *(const f32x4*)(F2h + j0 + 4);
            f32x4 fb0 = *(const f32x4*)(F2bh + j0);
            f32x4 fb1 = *(const f32x4*)(F2bh + j0 + 4);
            float p[8];
#pragma unroll
            for (int e = 0; e < 8; ++e) {
                float fe = (e < 4) ? fa0[e & 3] : fa1[e & 3];
                float fb = (e < 4) ? fb0[e & 3] : fb1[e & 3];
                float pe = exp2f(fmaxf(ra + fe, rb + fb));
                p[e] = (mbyte & (1u << e)) ? pe : 0.f;
            }
            union { unsigned int u[4]; short8 s8; } cv;
#pragma unroll
            for (int q = 0; q < 4; ++q)
                cv.u[q] = __builtin_amdgcn_perm(__float_as_uint(p[2 * q + 1]),
                                                __float_as_uint(p[2 * q]), 0x07060302u);
            __builtin_amdgcn_s_setprio(1);
            asum = __builtin_amdgcn_mfma_f32_32x32x16_bf16(cv.s8, ones, asum, 0, 0, 0);
#pragma unroll
            for (int ft = 0; ft < 4; ++ft) {
                int fr = ft * 32 + lrow;
                short8 bfrag = *(const short8*)(tb + fr * 128 + (((kk * 2 + kh) * 16) ^ ((fr & 7) << 4)));
                acc[ft] = __builtin_amdgcn_mfma_f32_32x32x16_bf16(cv.s8, bfrag, acc[ft], 0, 0, 0);
            }
            __builtin_amdgcn_s_setprio(0);
        }
    }

    // denominators in matching register slots (ones-column trick, r7/r8-verified)
    float dinv[16];
#pragma unroll
    for (int t = 0; t < 16; ++t)
        dinv[t] = (asum[t] > 0.f) ? (1.0f / asum[t]) : 0.f;

#pragma unroll
    for (int ft = 0; ft < 4; ++ft)
#pragma unroll
        for (int g = 0; g < 4; ++g)
#pragma unroll
            for (int rr = 0; rr < 4; ++rr) {
                int grow = rowbase + w * 32 + (g << 3) + (kh << 2) + rr;
                if (grow < NN) {
                    float v = acc[ft][g * 4 + rr] * dinv[g * 4 + rr];
                    v = (v > 0.f) ? v : (__expf(v) - 1.f);
                    x2[(size_t)grow * FTOT + h * HID + fh * 128 + ft * 32 + lrow] = f2bf(v);
                }
            }
}

// ---------------- GEMM2: split-K x8 -> f32 partials (verified r5) ----------------
__global__ __launch_bounds__(256, 2) void gemm_hc(const unsigned short* __restrict__ A,
                                                  const unsigned short* __restrict__ B,
                                                  float* __restrict__ pk) {
    int w = threadIdx.x >> 6, l = threadIdx.x & 63;
    int lrow = l & 31, kh = l >> 5;
    int q = blockIdx.y;
    int nbase = blockIdx.x * 128 + w * 32;
    int brow = nbase + lrow; if (brow > NN - 1) brow = NN - 1;
    f32x16 acc = (f32x16)0.0f;
    const short8* ap = (const short8*)(A + (size_t)lrow * FTOT + q * 256 + kh * 8);
    const short8* bp = (const short8*)(B + (size_t)brow * FTOT + q * 256 + kh * 8);
#pragma unroll
    for (int kk = 0; kk < 16; ++kk) {
        short8 af = ap[kk * 2];
        short8 bf = bp[kk * 2];
        acc = __builtin_amdgcn_mfma_f32_32x32x16_bf16(af, bf, acc, 0, 0, 0);
    }
    int i = nbase + lrow;
#pragma unroll
    for (int g = 0; g < 4; ++g) {
        int c0 = (g << 3) + (kh << 2);
#pragma unroll
        for (int r = 0; r < 4; ++r)
            pk[((size_t)q * NC + c0 + r) * NPAD + i] = acc[g * 4 + r];
    }
}

__global__ void merge_hc(const float* __restrict__ pk, unsigned short* __restrict__ hct) {
    int i = blockIdx.x * 256 + threadIdx.x;
    int c = blockIdx.y;
    if (i >= NPAD) return;
    float s = 0.f;
#pragma unroll
    for (int q = 0; q < 8; ++q) s += pk[((size_t)q * NC + c) * NPAD + i];
    hct[(size_t)c * NPAD + i] = f2bf(s);
}

// ---------------- classifier attention (verified r7/r8): barrier-free, j-split 4, ones dsum ----------------
__global__ __launch_bounds__(256) void cls_part(
    const unsigned short* __restrict__ hctb,
    const unsigned long long* __restrict__ mask,
    const float* __restrict__ RAc, const float* __restrict__ RBc,
    const float* __restrict__ F2c,
    float* __restrict__ pacc, float* __restrict__ pdsum)
{
    const int w = threadIdx.x >> 6, l = threadIdx.x & 63;
    const int lrow = l & 31, kh = l >> 5;
    const int q = blockIdx.y;
    const int rowbase = blockIdx.x * 128;
    const int myrow = rowbase + w * 32 + lrow;
    const bool act = myrow < NN;
    float ra = RAc[myrow], rb = RBc[myrow];
    const int JB0 = q * 24, JB1 = (JB0 + 24 < NJB) ? JB0 + 24 : NJB;
    const short8 ones = { (short)0x3F80, (short)0x3F80, (short)0x3F80, (short)0x3F80,
                          (short)0x3F80, (short)0x3F80, (short)0x3F80, (short)0x3F80 };
    f32x16 acc = (f32x16)0.0f;
    f32x16 asum = (f32x16)0.0f;

#pragma unroll 1
    for (int jb = JB0; jb < JB1; ++jb) {
        unsigned long long mword = act ? mask[(size_t)myrow * MSTR + jb] : 0ull;
#pragma unroll
        for (int kk = 0; kk < 4; ++kk) {
            short8 bfrag = *(const short8*)(hctb + (size_t)lrow * NPAD + jb * 64 + (kk * 2 + kh) * 8);
            unsigned int mbyte = (unsigned int)((mword >> (kk * 16 + kh * 8)) & 0xffull);
            int j0 = jb * 64 + kk * 16 + kh * 8;
            f32x4 fa0 = *(const f32x4*)(F2c + j0);
            f32x4 fa1 = *(const f32x4*)(F2c + j0 + 4);
            float p[8];
#pragma unroll
            for (int e = 0; e < 8; ++e) {
                float fe = (e < 4) ? fa0[e & 3] : fa1[e & 3];
                float pe = exp2f(fmaxf(ra + fe, rb + 0.2f * fe));
                p[e] = (mbyte & (1u << e)) ? pe : 0.f;
            }
            union { unsigned int u[4]; short8 s8; } cv;
#pragma unroll
            for (int t = 0; t < 4; ++t)
                cv.u[t] = __builtin_amdgcn_perm(__float_as_uint(p[2 * t + 1]),
                                                __float_as_uint(p[2 * t]), 0x07060302u);
            asum = __builtin_amdgcn_mfma_f32_32x32x16_bf16(cv.s8, ones, asum, 0, 0, 0);
            acc = __builtin_amdgcn_mfma_f32_32x32x16_bf16(cv.s8, bfrag, acc, 0, 0, 0);
        }
    }
#pragma unroll
    for (int g = 0; g < 4; ++g)
#pragma unroll
        for (int rr = 0; rr < 4; ++rr) {
            int i = rowbase + w * 32 + (g << 3) + (kh << 2) + rr;
            pacc[((size_t)q * NPAD + i) * NC + lrow] = acc[g * 4 + rr];
            if (lrow == 0) pdsum[(size_t)q * NPAD + i] = asum[g * 4 + rr];
        }
}

__global__ void cls_merge(const float* __restrict__ pacc, const float* __restrict__ pdsum,
                          float* __restrict__ outp) {
    int i = blockIdx.x * 8 + (threadIdx.x >> 5);
    int c = threadIdx.x & 31;
    if (i >= NN) return;
    float num = 0.f, den = 0.f;
#pragma unroll
    for (int q = 0; q < 4; ++q) {
        num += pacc[((size_t)q * NPAD + i) * NC + c];
        den += pdsum[(size_t)q * NPAD + i];
    }
    outp[(size_t)i * NC + c] = (den > 0.f) ? num / den : 0.f;
}

// ---------------- launcher ----------------
extern "C" void kernel_launch(void* const* d_in, const int* in_sizes, int n_in,
                              void* d_out, int out_size, void* d_ws, size_t ws_size,
                              hipStream_t stream) {
    const float* features = (const float*)d_in[0];
    const int*   adj      = (const int*)d_in[1];
    const float* W0       = (const float*)d_in[2];
    const float* a10      = (const float*)d_in[3];
    const float* a20      = (const float*)d_in[4];
    const float* Wc       = (const float*)d_in[5];
    const float* a1c      = (const float*)d_in[6];
    const float* a2c      = (const float*)d_in[7];
    float* out = (float*)d_out;

    char* p = (char*)d_ws;
    auto alloc = [&](size_t bytes) { char* r = p; p += (bytes + 255) & ~(size_t)255; return r; };
    unsigned long long* mask = (unsigned long long*)alloc((size_t)NN * MSTR * 8);
    unsigned short* Xbf = (unsigned short*)alloc((size_t)NN * DF * 2);
    unsigned short* Wt  = (unsigned short*)alloc((size_t)FTOT * DF * 2);
    unsigned short* Ht  = (unsigned short*)alloc((size_t)FTOT * NPAD * 2);
    unsigned short* x2  = (unsigned short*)alloc((size_t)NN * FTOT * 2);
    unsigned short* Wct = (unsigned short*)alloc((size_t)NC * FTOT * 2);
    unsigned short* hct = (unsigned short*)alloc((size_t)NC * NPAD * 2);
    float* f1  = (float*)alloc((size_t)NH * NPAD * 4);
    float* f2  = (float*)alloc((size_t)NH * NPAD * 4);
    float* RA  = (float*)alloc((size_t)NH * NPAD * 4);
    float* RB  = (float*)alloc((size_t)NH * NPAD * 4);
    float* F2b = (float*)alloc((size_t)NH * NPAD * 4);
    float* f1c  = (float*)alloc((size_t)NPAD * 4);
    float* f2c  = (float*)alloc((size_t)NPAD * 4);
    float* RAc  = (float*)alloc((size_t)NPAD * 4);
    float* RBc  = (float*)alloc((size_t)NPAD * 4);
    // overlays on dead Xbf+Wt (8.26 MB): pkhc 6.16 MB (gemm_hc), then pacc 3.08 MB + pdsum 96 KB (cls)
    float* pkhc  = (float*)Xbf;
    float* pacc  = (float*)Xbf;
    float* pdsum = pacc + (size_t)4 * NPAD * NC;

    pack_bits<<<dim3(3, NN), 256, 0, stream>>>(adj, (unsigned char*)mask);
    cast_x4<<<(NN * DF / 4 + 255) / 256, 256, 0, stream>>>(features, Xbf, NN * DF / 4);
    wt_pack<<<FTOT, 256, 0, stream>>>(W0, Wt);
    wct_pack<<<NC, 256, 0, stream>>>(Wc, Wct);

    gemm_h<<<dim3(NPAD / 128, FTOT / 128), 256, 0, stream>>>(Xbf, Wt, Ht);
    f12_kern<<<dim3((NPAD + 255) / 256, NH), 256, 0, stream>>>(Ht, a10, a20, f1, f2, HID);
    rarb_kern<<<NH, 256, 0, stream>>>(f1, f2, RA, RB);
    prep_f2b<<<(NH * NPAD + 255) / 256, 256, 0, stream>>>(f2, F2b, NH * NPAD);

    attn_main<<<dim3(32 * 2 * NH), 384, 0, stream>>>(Ht, mask, RA, RB, f2, F2b, x2);

    gemm_hc<<<dim3(NPAD / 128, 8), 256, 0, stream>>>(Wct, x2, pkhc);
    merge_hc<<<dim3((NPAD + 255) / 256, NC), 256, 0, stream>>>(pkhc, hct);
    f12_kern<<<dim3((NPAD + 255) / 256, 1), 256, 0, stream>>>(hct, a1c, a2c, f1c, f2c, NC);
    rarb_kern<<<1, 256, 0, stream>>>(f1c, f2c, RAc, RBc);

    cls_part<<<dim3(47, 4), 256, 0, stream>>>(hct, mask, RAc, RBc, f2c, pacc, pdsum);
    cls_merge<<<750, 256, 0, stream>>>(pacc, pdsum, out);
}

// Round 13
// 460.562 us; speedup vs baseline: 1.6412x; 1.4408x over previous
//
#include <hip/hip_runtime.h>
#include <hip/hip_bf16.h>

#define NN 6000
#define NPAD 6016      // 94*64
#define DF 512
#define HID 256
#define NH 8
#define NC 32
#define FTOT 2048
#define MSTR 96        // u64 words per mask row
#define NJB (NPAD / 64)
#define L2E 1.4426950408889634f

using short8 = __attribute__((ext_vector_type(8))) short;
using f32x16 = __attribute__((ext_vector_type(16))) float;
using f32x4  = __attribute__((ext_vector_type(4))) float;

__device__ __forceinline__ unsigned short f2bf(float f) {
    unsigned int u = __float_as_uint(f);
    return (unsigned short)((u + 0x7fffu + ((u >> 16) & 1u)) >> 16);
}
__device__ __forceinline__ float bf2f(unsigned short s) {
    return __uint_as_float(((unsigned int)s) << 16);
}
// async global->LDS, 16B per lane
__device__ __forceinline__ void gl16(const void* g, void* l) {
    __builtin_amdgcn_global_load_lds(
        (const __attribute__((address_space(1))) unsigned int*)g,
        (__attribute__((address_space(3))) unsigned int*)l, 16, 0, 0);
}

// ---------------- prep kernels (verified r3/r4) ----------------

__global__ void pack_bits(const int* __restrict__ adj, unsigned char* __restrict__ maskb) {
    int row = blockIdx.y;
    int b = blockIdx.x * 256 + threadIdx.x;     // byte index 0..767
    if (b >= 768) return;
    int j0 = b * 8;
    unsigned int v = 0;
    if (j0 + 7 < NN) {
        const int4* p = (const int4*)(adj + (size_t)row * NN + j0);
        int4 a = p[0], c = p[1];
        v = (unsigned)((a.x>0) | ((a.y>0)<<1) | ((a.z>0)<<2) | ((a.w>0)<<3)
          | ((c.x>0)<<4) | ((c.y>0)<<5) | ((c.z>0)<<6) | ((c.w>0)<<7));
    }
    maskb[(size_t)row * 768 + b] = (unsigned char)v;
}

__global__ void cast_x4(const float* __restrict__ x, unsigned short* __restrict__ xb, int n4) {
    int i = blockIdx.x * 256 + threadIdx.x;
    if (i >= n4) return;
    float4 v = ((const float4*)x)[i];
    unsigned long long pk = (unsigned long long)f2bf(v.x)
        | ((unsigned long long)f2bf(v.y) << 16)
        | ((unsigned long long)f2bf(v.z) << 32)
        | ((unsigned long long)f2bf(v.w) << 48);
    ((unsigned long long*)xb)[i] = pk;
}

__global__ void wt_pack(const float* __restrict__ W0, unsigned short* __restrict__ Wt) {
    int fp = blockIdx.x;                 // h*256+f
    int h = fp >> 8, f = fp & 255;
    for (int k = threadIdx.x; k < DF; k += 256)
        Wt[(size_t)fp * DF + k] = f2bf(W0[(((size_t)h * DF + k) << 8) | f]);
}

__global__ void wct_pack(const float* __restrict__ Wc, unsigned short* __restrict__ Wct) {
    int c = blockIdx.x;
    for (int k = threadIdx.x; k < FTOT; k += 256)
        Wct[(size_t)c * FTOT + k] = f2bf(Wc[(size_t)k * NC + c]);
}

// ---------------- GEMM1 (verified r3): Ht[f][i] = sum_k X[i][k] W[k][f] ----------------
__global__ __launch_bounds__(256, 2) void gemm_h(const unsigned short* __restrict__ A,
                                                 const unsigned short* __restrict__ B,
                                                 unsigned short* __restrict__ Ht) {
    __shared__ __align__(16) unsigned short As[128 * 64];
    __shared__ __align__(16) unsigned short Bs[128 * 64];
    const int w = threadIdx.x >> 6, l = threadIdx.x & 63;
    const int lrow = l & 31, kh = l >> 5;
    const int wm = w >> 1, wn = w & 1;
    const int mbase = blockIdx.x * 128, nbase = blockIdx.y * 128;
    const int srcc = (l & 7) ^ (l >> 3);
    f32x16 acc[2][2];
#pragma unroll
    for (int i = 0; i < 2; ++i)
#pragma unroll
        for (int j = 0; j < 2; ++j) acc[i][j] = (f32x16)0.0f;

#pragma unroll 1
    for (int kb = 0; kb < DF / 64; ++kb) {
        __syncthreads();
#pragma unroll
        for (int q = 0; q < 4; ++q) {
            int c = q * 4 + w;
            int r = c * 8 + (l >> 3);
            int arow = mbase + r; if (arow > NN - 1) arow = NN - 1;
            gl16(A + (size_t)arow * DF + kb * 64 + srcc * 8, (char*)As + c * 1024);
            gl16(B + (size_t)(nbase + r) * DF + kb * 64 + srcc * 8, (char*)Bs + c * 1024);
        }
        __syncthreads();
#pragma unroll
        for (int kk = 0; kk < 4; ++kk) {
            short8 av[2], bv[2];
#pragma unroll
            for (int mt = 0; mt < 2; ++mt) {
                int r = wm * 64 + mt * 32 + lrow;
                av[mt] = *(const short8*)((const char*)As + r * 128 + ((((kk << 1) | kh) ^ (r & 7)) << 4));
            }
#pragma unroll
            for (int ft = 0; ft < 2; ++ft) {
                int r = wn * 64 + ft * 32 + lrow;
                bv[ft] = *(const short8*)((const char*)Bs + r * 128 + ((((kk << 1) | kh) ^ (r & 7)) << 4));
            }
#pragma unroll
            for (int mt = 0; mt < 2; ++mt)
#pragma unroll
                for (int ft = 0; ft < 2; ++ft)
                    acc[mt][ft] = __builtin_amdgcn_mfma_f32_32x32x16_bf16(av[mt], bv[ft], acc[mt][ft], 0, 0, 0);
        }
    }
#pragma unroll
    for (int mt = 0; mt < 2; ++mt)
#pragma unroll
        for (int ft = 0; ft < 2; ++ft) {
            size_t n = nbase + wn * 64 + ft * 32 + lrow;
#pragma unroll
            for (int g = 0; g < 4; ++g) {
                int m0 = mbase + wm * 64 + mt * 32 + (g << 3) + (kh << 2);
                unsigned long long pk =
                    (unsigned long long)f2bf(acc[mt][ft][g * 4 + 0]) |
                    ((unsigned long long)f2bf(acc[mt][ft][g * 4 + 1]) << 16) |
                    ((unsigned long long)f2bf(acc[mt][ft][g * 4 + 2]) << 32) |
                    ((unsigned long long)f2bf(acc[mt][ft][g * 4 + 3]) << 48);
                *(unsigned long long*)(Ht + n * NPAD + m0) = pk;
            }
        }
}

// ---------------- f1/f2, pre-scaled by log2e (verified r6) ----------------
__global__ void f12_kern(const unsigned short* __restrict__ Ht, const float* __restrict__ a1,
                         const float* __restrict__ a2, float* __restrict__ f1, float* __restrict__ f2,
                         int fdim) {
    int h = blockIdx.y;
    int i = blockIdx.x * 256 + threadIdx.x;
    if (i >= NPAD) return;
    float s1 = 0.f, s2 = 0.f;
    const unsigned short* base = Ht + (size_t)h * fdim * NPAD + i;
    for (int f = 0; f < fdim; ++f) {
        float v = bf2f(base[(size_t)f * NPAD]);
        s1 = fmaf(v, a1[h * fdim + f], s1);
        s2 = fmaf(v, a2[h * fdim + f], s2);
    }
    f1[(size_t)h * NPAD + i] = s1 * L2E;
    f2[(size_t)h * NPAD + i] = s2 * L2E;
}

// per-head global max -> RA/RB (verified r5/r6)
__global__ void rarb_kern(const float* __restrict__ f1all, const float* __restrict__ f2all,
                          float* __restrict__ RA, float* __restrict__ RB) {
    int h = blockIdx.x;
    __shared__ float red[8];
    const float* f2h = f2all + (size_t)h * NPAD;
    float m = -3.0e38f;
    for (int i = threadIdx.x; i < NN; i += 256) m = fmaxf(m, f2h[i]);
    for (int off = 32; off; off >>= 1) m = fmaxf(m, __shfl_xor(m, off));
    if ((threadIdx.x & 63) == 0) red[threadIdx.x >> 6] = m;
    __syncthreads();
    if (threadIdx.x == 0)
        red[4] = fmaxf(fmaxf(red[0], red[1]), fmaxf(red[2], red[3]));
    __syncthreads();
    float Mh = red[4];
    for (int i = threadIdx.x; i < NPAD; i += 256) {
        float F1 = (i < NN) ? f1all[(size_t)h * NPAD + i] : 0.f;
        float t2 = F1 + Mh;
        float Mi = fmaxf(t2, 0.2f * t2);
        RA[(size_t)h * NPAD + i] = F1 - Mi;
        RB[(size_t)h * NPAD + i] = 0.2f * F1 - Mi;
    }
}

// NEW: E2F = exp2(f2), E2Fb = exp2(0.2*f2) — hoists ALL transcendentals out of the attn hot loop.
// exp2(max(ra+fe, rb+0.2fe)) == max(exp2(ra)*E2F[j], exp2(rb)*E2Fb[j])  (exp2 monotone; exact)
__global__ void exp_f2(const float* __restrict__ f2, float* __restrict__ E2F,
                       float* __restrict__ E2Fb, int n) {
    int i = blockIdx.x * 256 + threadIdx.x;
    if (i < n) { float v = f2[i]; E2F[i] = exp2f(v); E2Fb[i] = exp2f(0.2f * v); }
}

// ---------------- main attention (r8 skeleton byte-exact; P-path = product form) ----------------
// grid 752: h = bid&7 (head->XCD pin), fh = (bid>>3)&1, rowblk = bid>>4 (128 rows, 4 waves x 32).
// Per jb: STAGE(t+1) -> vmcnt(4) -> s_barrier (non-draining) -> compute(t). Triple buffer 48 KB.
__global__ __launch_bounds__(256, 3) void attn_main(
    const unsigned short* __restrict__ Ht,
    const unsigned long long* __restrict__ mask,
    const float* __restrict__ RA, const float* __restrict__ RB,
    const float* __restrict__ E2F, const float* __restrict__ E2Fb,
    unsigned short* __restrict__ x2)
{
    __shared__ __align__(16) unsigned short htile[3 * 128 * 64];   // 48 KB, swizzled [128][64] x3
    const int bid = blockIdx.x;
    const int h = bid & 7;
    const int fh = (bid >> 3) & 1;
    const int rowbase = (bid >> 4) * 128;
    const int w = threadIdx.x >> 6, l = threadIdx.x & 63;
    const int lrow = l & 31, kh = l >> 5;
    const int myrow = rowbase + w * 32 + lrow;
    const bool act = myrow < NN;
    const int rowc = act ? myrow : NN - 1;
    const unsigned short* Hh = Ht + ((size_t)h * HID + fh * 128) * NPAD;
    const float* E2Fh = E2F + (size_t)h * NPAD;
    const float* E2Fbh = E2Fb + (size_t)h * NPAD;
    const float era = exp2f(RA[(size_t)h * NPAD + rowc]);
    const float erb = exp2f(RB[(size_t)h * NPAD + rowc]);
    const int srcc = (l & 7) ^ (l >> 3);
    const short8 ones = { (short)0x3F80, (short)0x3F80, (short)0x3F80, (short)0x3F80,
                          (short)0x3F80, (short)0x3F80, (short)0x3F80, (short)0x3F80 };
    f32x16 acc[4];
    f32x16 asum = (f32x16)0.0f;
#pragma unroll
    for (int i = 0; i < 4; ++i) acc[i] = (f32x16)0.0f;

    auto STAGE = [&](int buf, int jb) {
#pragma unroll
        for (int q = 0; q < 4; ++q) {
            int c = q * 4 + w;                   // chunk 0..15
            int f = c * 8 + (l >> 3);            // tile row 0..127
            gl16(Hh + (size_t)f * NPAD + jb * 64 + srcc * 8, (char*)htile + buf * 16384 + c * 1024);
        }
    };

    STAGE(0, 0);
#pragma unroll 1
    for (int jb = 0; jb < NJB; ++jb) {
        if (jb + 1 < NJB) STAGE((jb + 1) % 3, jb + 1);     // depth-1 prefetch (4 gl16, static)
        asm volatile("s_waitcnt vmcnt(4)" ::: "memory");   // own S(jb) retired; prefetch in flight
        __builtin_amdgcn_sched_barrier(0);
        __builtin_amdgcn_s_barrier();                      // publish tile jb (non-draining)
        __builtin_amdgcn_sched_barrier(0);
        const char* tb = (const char*)htile + (jb % 3) * 16384;
        unsigned long long mw = mask[(size_t)rowc * MSTR + jb];
#pragma unroll
        for (int kk = 0; kk < 4; ++kk) {
            unsigned int mbyte = (unsigned int)((mw >> (kk * 16 + kh * 8)) & 0xffull);
            int j0 = jb * 64 + kk * 16 + kh * 8;
            f32x4 ea0 = *(const f32x4*)(E2Fh + j0);
            f32x4 ea1 = *(const f32x4*)(E2Fh + j0 + 4);
            f32x4 eb0 = *(const f32x4*)(E2Fbh + j0);
            f32x4 eb1 = *(const f32x4*)(E2Fbh + j0 + 4);
            float p[8];
#pragma unroll
            for (int e = 0; e < 8; ++e) {
                float fe = (e < 4) ? ea0[e & 3] : ea1[e & 3];
                float fb = (e < 4) ? eb0[e & 3] : eb1[e & 3];
                float pe = fmaxf(era * fe, erb * fb);      // == exp2(max(ra+f, rb+0.2f))
                p[e] = (mbyte & (1u << e)) ? pe : 0.f;
            }
            union { unsigned int u[4]; short8 s8; } cv;
#pragma unroll
            for (int q = 0; q < 4; ++q)
                cv.u[q] = __builtin_amdgcn_perm(__float_as_uint(p[2 * q + 1]),
                                                __float_as_uint(p[2 * q]), 0x07060302u);
            __builtin_amdgcn_s_setprio(1);
            asum = __builtin_amdgcn_mfma_f32_32x32x16_bf16(cv.s8, ones, asum, 0, 0, 0);
#pragma unroll
            for (int ft = 0; ft < 4; ++ft) {
                int fr = ft * 32 + lrow;
                short8 bfrag = *(const short8*)(tb + fr * 128 + (((kk * 2 + kh) * 16) ^ ((fr & 7) << 4)));
                acc[ft] = __builtin_amdgcn_mfma_f32_32x32x16_bf16(cv.s8, bfrag, acc[ft], 0, 0, 0);
            }
            __builtin_amdgcn_s_setprio(0);
        }
    }

    // denominators in matching register slots (ones-column trick, r7/r8-verified)
    float dinv[16];
#pragma unroll
    for (int t = 0; t < 16; ++t)
        dinv[t] = (asum[t] > 0.f) ? (1.0f / asum[t]) : 0.f;

#pragma unroll
    for (int ft = 0; ft < 4; ++ft)
#pragma unroll
        for (int g = 0; g < 4; ++g)
#pragma unroll
            for (int rr = 0; rr < 4; ++rr) {
                int grow = rowbase + w * 32 + (g << 3) + (kh << 2) + rr;
                if (grow < NN) {
                    float v = acc[ft][g * 4 + rr] * dinv[g * 4 + rr];
                    v = (v > 0.f) ? v : (__expf(v) - 1.f);
                    x2[(size_t)grow * FTOT + h * HID + fh * 128 + ft * 32 + lrow] = f2bf(v);
                }
            }
}

// ---------------- GEMM2: split-K x8 -> f32 partials (verified r5) ----------------
__global__ __launch_bounds__(256, 2) void gemm_hc(const unsigned short* __restrict__ A,
                                                  const unsigned short* __restrict__ B,
                                                  float* __restrict__ pk) {
    int w = threadIdx.x >> 6, l = threadIdx.x & 63;
    int lrow = l & 31, kh = l >> 5;
    int q = blockIdx.y;
    int nbase = blockIdx.x * 128 + w * 32;
    int brow = nbase + lrow; if (brow > NN - 1) brow = NN - 1;
    f32x16 acc = (f32x16)0.0f;
    const short8* ap = (const short8*)(A + (size_t)lrow * FTOT + q * 256 + kh * 8);
    const short8* bp = (const short8*)(B + (size_t)brow * FTOT + q * 256 + kh * 8);
#pragma unroll
    for (int kk = 0; kk < 16; ++kk) {
        short8 af = ap[kk * 2];
        short8 bf = bp[kk * 2];
        acc = __builtin_amdgcn_mfma_f32_32x32x16_bf16(af, bf, acc, 0, 0, 0);
    }
    int i = nbase + lrow;
#pragma unroll
    for (int g = 0; g < 4; ++g) {
        int c0 = (g << 3) + (kh << 2);
#pragma unroll
        for (int r = 0; r < 4; ++r)
            pk[((size_t)q * NC + c0 + r) * NPAD + i] = acc[g * 4 + r];
    }
}

__global__ void merge_hc(const float* __restrict__ pk, unsigned short* __restrict__ hct) {
    int i = blockIdx.x * 256 + threadIdx.x;
    int c = blockIdx.y;
    if (i >= NPAD) return;
    float s = 0.f;
#pragma unroll
    for (int q = 0; q < 8; ++q) s += pk[((size_t)q * NC + c) * NPAD + i];
    hct[(size_t)c * NPAD + i] = f2bf(s);
}

// ---------------- classifier attention (r7/r8 skeleton; P-path = product form) ----------------
__global__ __launch_bounds__(256) void cls_part(
    const unsigned short* __restrict__ hctb,
    const unsigned long long* __restrict__ mask,
    const float* __restrict__ RAc, const float* __restrict__ RBc,
    const float* __restrict__ E2Fc, const float* __restrict__ E2Fcb,
    float* __restrict__ pacc, float* __restrict__ pdsum)
{
    const int w = threadIdx.x >> 6, l = threadIdx.x & 63;
    const int lrow = l & 31, kh = l >> 5;
    const int q = blockIdx.y;
    const int rowbase = blockIdx.x * 128;
    const int myrow = rowbase + w * 32 + lrow;
    const bool act = myrow < NN;
    const float era = exp2f(RAc[myrow]);
    const float erb = exp2f(RBc[myrow]);
    const int JB0 = q * 24, JB1 = (JB0 + 24 < NJB) ? JB0 + 24 : NJB;
    const short8 ones = { (short)0x3F80, (short)0x3F80, (short)0x3F80, (short)0x3F80,
                          (short)0x3F80, (short)0x3F80, (short)0x3F80, (short)0x3F80 };
    f32x16 acc = (f32x16)0.0f;
    f32x16 asum = (f32x16)0.0f;

#pragma unroll 1
    for (int jb = JB0; jb < JB1; ++jb) {
        unsigned long long mword = act ? mask[(size_t)myrow * MSTR + jb] : 0ull;
#pragma unroll
        for (int kk = 0; kk < 4; ++kk) {
            short8 bfrag = *(const short8*)(hctb + (size_t)lrow * NPAD + jb * 64 + (kk * 2 + kh) * 8);
            unsigned int mbyte = (unsigned int)((mword >> (kk * 16 + kh * 8)) & 0xffull);
            int j0 = jb * 64 + kk * 16 + kh * 8;
            f32x4 ea0 = *(const f32x4*)(E2Fc + j0);
            f32x4 ea1 = *(const f32x4*)(E2Fc + j0 + 4);
            f32x4 eb0 = *(const f32x4*)(E2Fcb + j0);
            f32x4 eb1 = *(const f32x4*)(E2Fcb + j0 + 4);
            float p[8];
#pragma unroll
            for (int e = 0; e < 8; ++e) {
                float fe = (e < 4) ? ea0[e & 3] : ea1[e & 3];
                float fb = (e < 4) ? eb0[e & 3] : eb1[e & 3];
                float pe = fmaxf(era * fe, erb * fb);
                p[e] = (mbyte & (1u << e)) ? pe : 0.f;
            }
            union { unsigned int u[4]; short8 s8; } cv;
#pragma unroll
            for (int t = 0; t < 4; ++t)
                cv.u[t] = __builtin_amdgcn_perm(__float_as_uint(p[2 * t + 1]),
                                                __float_as_uint(p[2 * t]), 0x07060302u);
            asum = __builtin_amdgcn_mfma_f32_32x32x16_bf16(cv.s8, ones, asum, 0, 0, 0);
            acc = __builtin_amdgcn_mfma_f32_32x32x16_bf16(cv.s8, bfrag, acc, 0, 0, 0);
        }
    }
#pragma unroll
    for (int g = 0; g < 4; ++g)
#pragma unroll
        for (int rr = 0; rr < 4; ++rr) {
            int i = rowbase + w * 32 + (g << 3) + (kh << 2) + rr;
            pacc[((size_t)q * NPAD + i) * NC + lrow] = acc[g * 4 + rr];
            if (lrow == 0) pdsum[(size_t)q * NPAD + i] = asum[g * 4 + rr];
        }
}

__global__ void cls_merge(const float* __restrict__ pacc, const float* __restrict__ pdsum,
                          float* __restrict__ outp) {
    int i = blockIdx.x * 8 + (threadIdx.x >> 5);
    int c = threadIdx.x & 31;
    if (i >= NN) return;
    float num = 0.f, den = 0.f;
#pragma unroll
    for (int q = 0; q < 4; ++q) {
        num += pacc[((size_t)q * NPAD + i) * NC + c];
        den += pdsum[(size_t)q * NPAD + i];
    }
    outp[(size_t)i * NC + c] = (den > 0.f) ? num / den : 0.f;
}

// ---------------- launcher ----------------
extern "C" void kernel_launch(void* const* d_in, const int* in_sizes, int n_in,
                              void* d_out, int out_size, void* d_ws, size_t ws_size,
                              hipStream_t stream) {
    const float* features = (const float*)d_in[0];
    const int*   adj      = (const int*)d_in[1];
    const float* W0       = (const float*)d_in[2];
    const float* a10      = (const float*)d_in[3];
    const float* a20      = (const float*)d_in[4];
    const float* Wc       = (const float*)d_in[5];
    const float* a1c      = (const float*)d_in[6];
    const float* a2c      = (const float*)d_in[7];
    float* out = (float*)d_out;

    char* p = (char*)d_ws;
    auto alloc = [&](size_t bytes) { char* r = p; p += (bytes + 255) & ~(size_t)255; return r; };
    unsigned long long* mask = (unsigned long long*)alloc((size_t)NN * MSTR * 8);
    unsigned short* Xbf = (unsigned short*)alloc((size_t)NN * DF * 2);
    unsigned short* Wt  = (unsigned short*)alloc((size_t)FTOT * DF * 2);
    unsigned short* Ht  = (unsigned short*)alloc((size_t)FTOT * NPAD * 2);
    unsigned short* x2  = (unsigned short*)alloc((size_t)NN * FTOT * 2);
    unsigned short* Wct = (unsigned short*)alloc((size_t)NC * FTOT * 2);
    unsigned short* hct = (unsigned short*)alloc((size_t)NC * NPAD * 2);
    float* f1  = (float*)alloc((size_t)NH * NPAD * 4);
    float* f2  = (float*)alloc((size_t)NH * NPAD * 4);
    float* RA  = (float*)alloc((size_t)NH * NPAD * 4);
    float* RB  = (float*)alloc((size_t)NH * NPAD * 4);
    float* E2F  = (float*)alloc((size_t)NH * NPAD * 4);
    float* E2Fb = (float*)alloc((size_t)NH * NPAD * 4);
    float* f1c  = (float*)alloc((size_t)NPAD * 4);
    float* f2c  = (float*)alloc((size_t)NPAD * 4);
    float* RAc  = (float*)alloc((size_t)NPAD * 4);
    float* RBc  = (float*)alloc((size_t)NPAD * 4);
    float* E2Fc  = (float*)alloc((size_t)NPAD * 4);
    float* E2Fcb = (float*)alloc((size_t)NPAD * 4);
    // overlays on dead Xbf+Wt (8.26 MB): pkhc 6.16 MB (gemm_hc), then pacc 3.08 MB + pdsum 96 KB (cls)
    float* pkhc  = (float*)Xbf;
    float* pacc  = (float*)Xbf;
    float* pdsum = pacc + (size_t)4 * NPAD * NC;

    pack_bits<<<dim3(3, NN), 256, 0, stream>>>(adj, (unsigned char*)mask);
    cast_x4<<<(NN * DF / 4 + 255) / 256, 256, 0, stream>>>(features, Xbf, NN * DF / 4);
    wt_pack<<<FTOT, 256, 0, stream>>>(W0, Wt);
    wct_pack<<<NC, 256, 0, stream>>>(Wc, Wct);

    gemm_h<<<dim3(NPAD / 128, FTOT / 128), 256, 0, stream>>>(Xbf, Wt, Ht);
    f12_kern<<<dim3((NPAD + 255) / 256, NH), 256, 0, stream>>>(Ht, a10, a20, f1, f2, HID);
    rarb_kern<<<NH, 256, 0, stream>>>(f1, f2, RA, RB);
    exp_f2<<<(NH * NPAD + 255) / 256, 256, 0, stream>>>(f2, E2F, E2Fb, NH * NPAD);

    attn_main<<<dim3(47 * 2 * NH), 256, 0, stream>>>(Ht, mask, RA, RB, E2F, E2Fb, x2);

    gemm_hc<<<dim3(NPAD / 128, 8), 256, 0, stream>>>(Wct, x2, pkhc);
    merge_hc<<<dim3((NPAD + 255) / 256, NC), 256, 0, stream>>>(pkhc, hct);
    f12_kern<<<dim3((NPAD + 255) / 256, 1), 256, 0, stream>>>(hct, a1c, a2c, f1c, f2c, NC);
    rarb_kern<<<1, 256, 0, stream>>>(f1c, f2c, RAc, RBc);
    exp_f2<<<(NPAD + 255) / 256, 256, 0, stream>>>(f2c, E2Fc, E2Fcb, NPAD);

    cls_part<<<dim3(47, 4), 256, 0, stream>>>(hct, mask, RAc, RBc, E2Fc, E2Fcb, pacc, pdsum);
    cls_merge<<<750, 256, 0, stream>>>(pacc, pdsum, out);
}

// Round 14
// 448.700 us; speedup vs baseline: 1.6846x; 1.0264x over previous
//
#include <hip/hip_runtime.h>
#include <hip/hip_bf16.h>

#define NN 6000
#define NPAD 6016      // 94*64
#define DF 512
#define HID 256
#define NH 8
#define NC 32
#define FTOT 2048
#define MSTR 96        // u64 words per mask row
#define NJB (NPAD / 64)
#define L2E 1.4426950408889634f

using short8 = __attribute__((ext_vector_type(8))) short;
using f32x16 = __attribute__((ext_vector_type(16))) float;
using f32x4  = __attribute__((ext_vector_type(4))) float;

__device__ __forceinline__ unsigned short f2bf(float f) {
    unsigned int u = __float_as_uint(f);
    return (unsigned short)((u + 0x7fffu + ((u >> 16) & 1u)) >> 16);
}
__device__ __forceinline__ float bf2f(unsigned short s) {
    return __uint_as_float(((unsigned int)s) << 16);
}
// async global->LDS, 16B per lane
__device__ __forceinline__ void gl16(const void* g, void* l) {
    __builtin_amdgcn_global_load_lds(
        (const __attribute__((address_space(1))) unsigned int*)g,
        (__attribute__((address_space(3))) unsigned int*)l, 16, 0, 0);
}

// ---------------- prep kernels (verified r3/r4) ----------------

__global__ void pack_bits(const int* __restrict__ adj, unsigned char* __restrict__ maskb) {
    int row = blockIdx.y;
    int b = blockIdx.x * 256 + threadIdx.x;     // byte index 0..767
    if (b >= 768) return;
    int j0 = b * 8;
    unsigned int v = 0;
    if (j0 + 7 < NN) {
        const int4* p = (const int4*)(adj + (size_t)row * NN + j0);
        int4 a = p[0], c = p[1];
        v = (unsigned)((a.x>0) | ((a.y>0)<<1) | ((a.z>0)<<2) | ((a.w>0)<<3)
          | ((c.x>0)<<4) | ((c.y>0)<<5) | ((c.z>0)<<6) | ((c.w>0)<<7));
    }
    maskb[(size_t)row * 768 + b] = (unsigned char)v;
}

__global__ void cast_x4(const float* __restrict__ x, unsigned short* __restrict__ xb, int n4) {
    int i = blockIdx.x * 256 + threadIdx.x;
    if (i >= n4) return;
    float4 v = ((const float4*)x)[i];
    unsigned long long pk = (unsigned long long)f2bf(v.x)
        | ((unsigned long long)f2bf(v.y) << 16)
        | ((unsigned long long)f2bf(v.z) << 32)
        | ((unsigned long long)f2bf(v.w) << 48);
    ((unsigned long long*)xb)[i] = pk;
}

__global__ void wt_pack(const float* __restrict__ W0, unsigned short* __restrict__ Wt) {
    int fp = blockIdx.x;                 // h*256+f
    int h = fp >> 8, f = fp & 255;
    for (int k = threadIdx.x; k < DF; k += 256)
        Wt[(size_t)fp * DF + k] = f2bf(W0[(((size_t)h * DF + k) << 8) | f]);
}

__global__ void wct_pack(const float* __restrict__ Wc, unsigned short* __restrict__ Wct) {
    int c = blockIdx.x;
    for (int k = threadIdx.x; k < FTOT; k += 256)
        Wct[(size_t)c * FTOT + k] = f2bf(Wc[(size_t)k * NC + c]);
}

// ---------------- GEMM1 (verified r3): Ht[f][i] = sum_k X[i][k] W[k][f] ----------------
__global__ __launch_bounds__(256, 2) void gemm_h(const unsigned short* __restrict__ A,
                                                 const unsigned short* __restrict__ B,
                                                 unsigned short* __restrict__ Ht) {
    __shared__ __align__(16) unsigned short As[128 * 64];
    __shared__ __align__(16) unsigned short Bs[128 * 64];
    const int w = threadIdx.x >> 6, l = threadIdx.x & 63;
    const int lrow = l & 31, kh = l >> 5;
    const int wm = w >> 1, wn = w & 1;
    const int mbase = blockIdx.x * 128, nbase = blockIdx.y * 128;
    const int srcc = (l & 7) ^ (l >> 3);
    f32x16 acc[2][2];
#pragma unroll
    for (int i = 0; i < 2; ++i)
#pragma unroll
        for (int j = 0; j < 2; ++j) acc[i][j] = (f32x16)0.0f;

#pragma unroll 1
    for (int kb = 0; kb < DF / 64; ++kb) {
        __syncthreads();
#pragma unroll
        for (int q = 0; q < 4; ++q) {
            int c = q * 4 + w;
            int r = c * 8 + (l >> 3);
            int arow = mbase + r; if (arow > NN - 1) arow = NN - 1;
            gl16(A + (size_t)arow * DF + kb * 64 + srcc * 8, (char*)As + c * 1024);
            gl16(B + (size_t)(nbase + r) * DF + kb * 64 + srcc * 8, (char*)Bs + c * 1024);
        }
        __syncthreads();
#pragma unroll
        for (int kk = 0; kk < 4; ++kk) {
            short8 av[2], bv[2];
#pragma unroll
            for (int mt = 0; mt < 2; ++mt) {
                int r = wm * 64 + mt * 32 + lrow;
                av[mt] = *(const short8*)((const char*)As + r * 128 + ((((kk << 1) | kh) ^ (r & 7)) << 4));
            }
#pragma unroll
            for (int ft = 0; ft < 2; ++ft) {
                int r = wn * 64 + ft * 32 + lrow;
                bv[ft] = *(const short8*)((const char*)Bs + r * 128 + ((((kk << 1) | kh) ^ (r & 7)) << 4));
            }
#pragma unroll
            for (int mt = 0; mt < 2; ++mt)
#pragma unroll
                for (int ft = 0; ft < 2; ++ft)
                    acc[mt][ft] = __builtin_amdgcn_mfma_f32_32x32x16_bf16(av[mt], bv[ft], acc[mt][ft], 0, 0, 0);
        }
    }
#pragma unroll
    for (int mt = 0; mt < 2; ++mt)
#pragma unroll
        for (int ft = 0; ft < 2; ++ft) {
            size_t n = nbase + wn * 64 + ft * 32 + lrow;
#pragma unroll
            for (int g = 0; g < 4; ++g) {
                int m0 = mbase + wm * 64 + mt * 32 + (g << 3) + (kh << 2);
                unsigned long long pk =
                    (unsigned long long)f2bf(acc[mt][ft][g * 4 + 0]) |
                    ((unsigned long long)f2bf(acc[mt][ft][g * 4 + 1]) << 16) |
                    ((unsigned long long)f2bf(acc[mt][ft][g * 4 + 2]) << 32) |
                    ((unsigned long long)f2bf(acc[mt][ft][g * 4 + 3]) << 48);
                *(unsigned long long*)(Ht + n * NPAD + m0) = pk;
            }
        }
}

// ---------------- f1/f2, pre-scaled by log2e (verified r6) ----------------
__global__ void f12_kern(const unsigned short* __restrict__ Ht, const float* __restrict__ a1,
                         const float* __restrict__ a2, float* __restrict__ f1, float* __restrict__ f2,
                         int fdim) {
    int h = blockIdx.y;
    int i = blockIdx.x * 256 + threadIdx.x;
    if (i >= NPAD) return;
    float s1 = 0.f, s2 = 0.f;
    const unsigned short* base = Ht + (size_t)h * fdim * NPAD + i;
    for (int f = 0; f < fdim; ++f) {
        float v = bf2f(base[(size_t)f * NPAD]);
        s1 = fmaf(v, a1[h * fdim + f], s1);
        s2 = fmaf(v, a2[h * fdim + f], s2);
    }
    f1[(size_t)h * NPAD + i] = s1 * L2E;
    f2[(size_t)h * NPAD + i] = s2 * L2E;
}

// per-head global max -> RA/RB + E2F/E2Fb (r5/r6-verified rarb + r13-verified exp hoist, fused)
__global__ void rarb_kern(const float* __restrict__ f1all, const float* __restrict__ f2all,
                          float* __restrict__ RA, float* __restrict__ RB,
                          float* __restrict__ E2F, float* __restrict__ E2Fb) {
    int h = blockIdx.x;
    __shared__ float red[8];
    const float* f2h = f2all + (size_t)h * NPAD;
    float m = -3.0e38f;
    for (int i = threadIdx.x; i < NN; i += 256) m = fmaxf(m, f2h[i]);
    for (int off = 32; off; off >>= 1) m = fmaxf(m, __shfl_xor(m, off));
    if ((threadIdx.x & 63) == 0) red[threadIdx.x >> 6] = m;
    __syncthreads();
    if (threadIdx.x == 0)
        red[4] = fmaxf(fmaxf(red[0], red[1]), fmaxf(red[2], red[3]));
    __syncthreads();
    float Mh = red[4];
    for (int i = threadIdx.x; i < NPAD; i += 256) {
        float F1 = (i < NN) ? f1all[(size_t)h * NPAD + i] : 0.f;
        float t2 = F1 + Mh;
        float Mi = fmaxf(t2, 0.2f * t2);
        RA[(size_t)h * NPAD + i] = F1 - Mi;
        RB[(size_t)h * NPAD + i] = 0.2f * F1 - Mi;
        float v2 = f2h[i];
        E2F[(size_t)h * NPAD + i] = exp2f(v2);
        E2Fb[(size_t)h * NPAD + i] = exp2f(0.2f * v2);
    }
}

// ---------------- main attention (r13 skeleton; LDS swizzle extended with row-bit-3) ----------------
// grid 752: h = bid&7 (head->XCD pin), fh = (bid>>3)&1, rowblk = bid>>4 (128 rows, 4 waves x 32).
// Per jb: STAGE(t+1) -> vmcnt(4) -> s_barrier (non-draining) -> compute(t). Triple buffer 48 KB.
// Swizzle involution now includes row bit 3: store srcq=(l&7)^(l>>3)^((c&1)<<2);
// read slot=(kk*2+kh)^(fr&7)^(((fr>>3)&1)<<2). 4-way read conflict -> 2-way (free, m136).
__global__ __launch_bounds__(256, 3) void attn_main(
    const unsigned short* __restrict__ Ht,
    const unsigned long long* __restrict__ mask,
    const float* __restrict__ RA, const float* __restrict__ RB,
    const float* __restrict__ E2F, const float* __restrict__ E2Fb,
    unsigned short* __restrict__ x2)
{
    __shared__ __align__(16) unsigned short htile[3 * 128 * 64];   // 48 KB, swizzled [128][64] x3
    const int bid = blockIdx.x;
    const int h = bid & 7;
    const int fh = (bid >> 3) & 1;
    const int rowbase = (bid >> 4) * 128;
    const int w = threadIdx.x >> 6, l = threadIdx.x & 63;
    const int lrow = l & 31, kh = l >> 5;
    const int myrow = rowbase + w * 32 + lrow;
    const bool act = myrow < NN;
    const int rowc = act ? myrow : NN - 1;
    const unsigned short* Hh = Ht + ((size_t)h * HID + fh * 128) * NPAD;
    const float* E2Fh = E2F + (size_t)h * NPAD;
    const float* E2Fbh = E2Fb + (size_t)h * NPAD;
    const float era = exp2f(RA[(size_t)h * NPAD + rowc]);
    const float erb = exp2f(RB[(size_t)h * NPAD + rowc]);
    const short8 ones = { (short)0x3F80, (short)0x3F80, (short)0x3F80, (short)0x3F80,
                          (short)0x3F80, (short)0x3F80, (short)0x3F80, (short)0x3F80 };
    f32x16 acc[4];
    f32x16 asum = (f32x16)0.0f;
#pragma unroll
    for (int i = 0; i < 4; ++i) acc[i] = (f32x16)0.0f;

    auto STAGE = [&](int buf, int jb) {
#pragma unroll
        for (int q = 0; q < 4; ++q) {
            int c = q * 4 + w;                   // chunk 0..15
            int f = c * 8 + (l >> 3);            // tile row 0..127
            int srcq = (l & 7) ^ (l >> 3) ^ ((c & 1) << 2);   // involution incl. row bit 3
            gl16(Hh + (size_t)f * NPAD + jb * 64 + srcq * 8, (char*)htile + buf * 16384 + c * 1024);
        }
    };

    STAGE(0, 0);
#pragma unroll 1
    for (int jb = 0; jb < NJB; ++jb) {
        if (jb + 1 < NJB) STAGE((jb + 1) % 3, jb + 1);     // depth-1 prefetch (4 gl16, static)
        asm volatile("s_waitcnt vmcnt(4)" ::: "memory");   // own S(jb) retired; prefetch in flight
        __builtin_amdgcn_sched_barrier(0);
        __builtin_amdgcn_s_barrier();                      // publish tile jb (non-draining)
        __builtin_amdgcn_sched_barrier(0);
        const char* tb = (const char*)htile + (jb % 3) * 16384;
        unsigned long long mw = mask[(size_t)rowc * MSTR + jb];
#pragma unroll
        for (int kk = 0; kk < 4; ++kk) {
            unsigned int mbyte = (unsigned int)((mw >> (kk * 16 + kh * 8)) & 0xffull);
            int j0 = jb * 64 + kk * 16 + kh * 8;
            f32x4 ea0 = *(const f32x4*)(E2Fh + j0);
            f32x4 ea1 = *(const f32x4*)(E2Fh + j0 + 4);
            f32x4 eb0 = *(const f32x4*)(E2Fbh + j0);
            f32x4 eb1 = *(const f32x4*)(E2Fbh + j0 + 4);
            float p[8];
#pragma unroll
            for (int e = 0; e < 8; ++e) {
                float fe = (e < 4) ? ea0[e & 3] : ea1[e & 3];
                float fb = (e < 4) ? eb0[e & 3] : eb1[e & 3];
                float pe = fmaxf(era * fe, erb * fb);      // == exp2(max(ra+f, rb+0.2f))
                p[e] = (mbyte & (1u << e)) ? pe : 0.f;
            }
            union { unsigned int u[4]; short8 s8; } cv;
#pragma unroll
            for (int q = 0; q < 4; ++q)
                cv.u[q] = __builtin_amdgcn_perm(__float_as_uint(p[2 * q + 1]),
                                                __float_as_uint(p[2 * q]), 0x07060302u);
            __builtin_amdgcn_s_setprio(1);
            asum = __builtin_amdgcn_mfma_f32_32x32x16_bf16(cv.s8, ones, asum, 0, 0, 0);
#pragma unroll
            for (int ft = 0; ft < 4; ++ft) {
                int fr = ft * 32 + lrow;
                int slot = ((kk * 2 + kh) ^ (fr & 7) ^ (((fr >> 3) & 1) << 2));
                short8 bfrag = *(const short8*)(tb + fr * 128 + (slot << 4));
                acc[ft] = __builtin_amdgcn_mfma_f32_32x32x16_bf16(cv.s8, bfrag, acc[ft], 0, 0, 0);
            }
            __builtin_amdgcn_s_setprio(0);
        }
    }

    // denominators in matching register slots (ones-column trick, r7/r8-verified)
    float dinv[16];
#pragma unroll
    for (int t = 0; t < 16; ++t)
        dinv[t] = (asum[t] > 0.f) ? (1.0f / asum[t]) : 0.f;

#pragma unroll
    for (int ft = 0; ft < 4; ++ft)
#pragma unroll
        for (int g = 0; g < 4; ++g)
#pragma unroll
            for (int rr = 0; rr < 4; ++rr) {
                int grow = rowbase + w * 32 + (g << 3) + (kh << 2) + rr;
                if (grow < NN) {
                    float v = acc[ft][g * 4 + rr] * dinv[g * 4 + rr];
                    v = (v > 0.f) ? v : (__expf(v) - 1.f);
                    x2[(size_t)grow * FTOT + h * HID + fh * 128 + ft * 32 + lrow] = f2bf(v);
                }
            }
}

// ---------------- GEMM2: split-K x8 -> f32 partials (verified r5) ----------------
__global__ __launch_bounds__(256, 2) void gemm_hc(const unsigned short* __restrict__ A,
                                                  const unsigned short* __restrict__ B,
                                                  float* __restrict__ pk) {
    int w = threadIdx.x >> 6, l = threadIdx.x & 63;
    int lrow = l & 31, kh = l >> 5;
    int q = blockIdx.y;
    int nbase = blockIdx.x * 128 + w * 32;
    int brow = nbase + lrow; if (brow > NN - 1) brow = NN - 1;
    f32x16 acc = (f32x16)0.0f;
    const short8* ap = (const short8*)(A + (size_t)lrow * FTOT + q * 256 + kh * 8);
    const short8* bp = (const short8*)(B + (size_t)brow * FTOT + q * 256 + kh * 8);
#pragma unroll
    for (int kk = 0; kk < 16; ++kk) {
        short8 af = ap[kk * 2];
        short8 bf = bp[kk * 2];
        acc = __builtin_amdgcn_mfma_f32_32x32x16_bf16(af, bf, acc, 0, 0, 0);
    }
    int i = nbase + lrow;
#pragma unroll
    for (int g = 0; g < 4; ++g) {
        int c0 = (g << 3) + (kh << 2);
#pragma unroll
        for (int r = 0; r < 4; ++r)
            pk[((size_t)q * NC + c0 + r) * NPAD + i] = acc[g * 4 + r];
    }
}

__global__ void merge_hc(const float* __restrict__ pk, unsigned short* __restrict__ hct) {
    int i = blockIdx.x * 256 + threadIdx.x;
    int c = blockIdx.y;
    if (i >= NPAD) return;
    float s = 0.f;
#pragma unroll
    for (int q = 0; q < 8; ++q) s += pk[((size_t)q * NC + c) * NPAD + i];
    hct[(size_t)c * NPAD + i] = f2bf(s);
}

// ---------------- classifier attention (r13 P-path; j-split 8 per r6-verified split axis) ----------------
__global__ __launch_bounds__(256) void cls_part(
    const unsigned short* __restrict__ hctb,
    const unsigned long long* __restrict__ mask,
    const float* __restrict__ RAc, const float* __restrict__ RBc,
    const float* __restrict__ E2Fc, const float* __restrict__ E2Fcb,
    float* __restrict__ pacc, float* __restrict__ pdsum)
{
    const int w = threadIdx.x >> 6, l = threadIdx.x & 63;
    const int lrow = l & 31, kh = l >> 5;
    const int q = blockIdx.y;
    const int rowbase = blockIdx.x * 128;
    const int myrow = rowbase + w * 32 + lrow;
    const bool act = myrow < NN;
    const float era = exp2f(RAc[myrow]);
    const float erb = exp2f(RBc[myrow]);
    const int JB0 = q * 12, JB1 = (JB0 + 12 < NJB) ? JB0 + 12 : NJB;
    const short8 ones = { (short)0x3F80, (short)0x3F80, (short)0x3F80, (short)0x3F80,
                          (short)0x3F80, (short)0x3F80, (short)0x3F80, (short)0x3F80 };
    f32x16 acc = (f32x16)0.0f;
    f32x16 asum = (f32x16)0.0f;

#pragma unroll 1
    for (int jb = JB0; jb < JB1; ++jb) {
        unsigned long long mword = act ? mask[(size_t)myrow * MSTR + jb] : 0ull;
#pragma unroll
        for (int kk = 0; kk < 4; ++kk) {
            short8 bfrag = *(const short8*)(hctb + (size_t)lrow * NPAD + jb * 64 + (kk * 2 + kh) * 8);
            unsigned int mbyte = (unsigned int)((mword >> (kk * 16 + kh * 8)) & 0xffull);
            int j0 = jb * 64 + kk * 16 + kh * 8;
            f32x4 ea0 = *(const f32x4*)(E2Fc + j0);
            f32x4 ea1 = *(const f32x4*)(E2Fc + j0 + 4);
            f32x4 eb0 = *(const f32x4*)(E2Fcb + j0);
            f32x4 eb1 = *(const f32x4*)(E2Fcb + j0 + 4);
            float p[8];
#pragma unroll
            for (int e = 0; e < 8; ++e) {
                float fe = (e < 4) ? ea0[e & 3] : ea1[e & 3];
                float fb = (e < 4) ? eb0[e & 3] : eb1[e & 3];
                float pe = fmaxf(era * fe, erb * fb);
                p[e] = (mbyte & (1u << e)) ? pe : 0.f;
            }
            union { unsigned int u[4]; short8 s8; } cv;
#pragma unroll
            for (int t = 0; t < 4; ++t)
                cv.u[t] = __builtin_amdgcn_perm(__float_as_uint(p[2 * t + 1]),
                                                __float_as_uint(p[2 * t]), 0x07060302u);
            asum = __builtin_amdgcn_mfma_f32_32x32x16_bf16(cv.s8, ones, asum, 0, 0, 0);
            acc = __builtin_amdgcn_mfma_f32_32x32x16_bf16(cv.s8, bfrag, acc, 0, 0, 0);
        }
    }
#pragma unroll
    for (int g = 0; g < 4; ++g)
#pragma unroll
        for (int rr = 0; rr < 4; ++rr) {
            int i = rowbase + w * 32 + (g << 3) + (kh << 2) + rr;
            pacc[((size_t)q * NPAD + i) * NC + lrow] = acc[g * 4 + rr];
            if (lrow == 0) pdsum[(size_t)q * NPAD + i] = asum[g * 4 + rr];
        }
}

__global__ void cls_merge(const float* __restrict__ pacc, const float* __restrict__ pdsum,
                          float* __restrict__ outp) {
    int i = blockIdx.x * 8 + (threadIdx.x >> 5);
    int c = threadIdx.x & 31;
    if (i >= NN) return;
    float num = 0.f, den = 0.f;
#pragma unroll
    for (int q = 0; q < 8; ++q) {
        num += pacc[((size_t)q * NPAD + i) * NC + c];
        den += pdsum[(size_t)q * NPAD + i];
    }
    outp[(size_t)i * NC + c] = (den > 0.f) ? num / den : 0.f;
}

// ---------------- launcher ----------------
extern "C" void kernel_launch(void* const* d_in, const int* in_sizes, int n_in,
                              void* d_out, int out_size, void* d_ws, size_t ws_size,
                              hipStream_t stream) {
    const float* features = (const float*)d_in[0];
    const int*   adj      = (const int*)d_in[1];
    const float* W0       = (const float*)d_in[2];
    const float* a10      = (const float*)d_in[3];
    const float* a20      = (const float*)d_in[4];
    const float* Wc       = (const float*)d_in[5];
    const float* a1c      = (const float*)d_in[6];
    const float* a2c      = (const float*)d_in[7];
    float* out = (float*)d_out;

    char* p = (char*)d_ws;
    auto alloc = [&](size_t bytes) { char* r = p; p += (bytes + 255) & ~(size_t)255; return r; };
    unsigned long long* mask = (unsigned long long*)alloc((size_t)NN * MSTR * 8);
    unsigned short* Xbf = (unsigned short*)alloc((size_t)NN * DF * 2);
    unsigned short* Wt  = (unsigned short*)alloc((size_t)FTOT * DF * 2);
    unsigned short* Ht  = (unsigned short*)alloc((size_t)FTOT * NPAD * 2);
    unsigned short* x2  = (unsigned short*)alloc((size_t)NN * FTOT * 2);
    unsigned short* Wct = (unsigned short*)alloc((size_t)NC * FTOT * 2);
    unsigned short* hct = (unsigned short*)alloc((size_t)NC * NPAD * 2);
    float* f1  = (float*)alloc((size_t)NH * NPAD * 4);
    float* f2  = (float*)alloc((size_t)NH * NPAD * 4);
    float* RA  = (float*)alloc((size_t)NH * NPAD * 4);
    float* RB  = (float*)alloc((size_t)NH * NPAD * 4);
    float* E2F  = (float*)alloc((size_t)NH * NPAD * 4);
    float* E2Fb = (float*)alloc((size_t)NH * NPAD * 4);
    float* f1c  = (float*)alloc((size_t)NPAD * 4);
    float* f2c  = (float*)alloc((size_t)NPAD * 4);
    float* RAc  = (float*)alloc((size_t)NPAD * 4);
    float* RBc  = (float*)alloc((size_t)NPAD * 4);
    float* E2Fc  = (float*)alloc((size_t)NPAD * 4);
    float* E2Fcb = (float*)alloc((size_t)NPAD * 4);
    // overlays on dead Xbf+Wt (8.26 MB): pkhc 6.16 MB (gemm_hc), then pacc 6.16 MB + pdsum 192 KB (cls)
    float* pkhc  = (float*)Xbf;
    float* pacc  = (float*)Xbf;
    float* pdsum = pacc + (size_t)8 * NPAD * NC;

    pack_bits<<<dim3(3, NN), 256, 0, stream>>>(adj, (unsigned char*)mask);
    cast_x4<<<(NN * DF / 4 + 255) / 256, 256, 0, stream>>>(features, Xbf, NN * DF / 4);
    wt_pack<<<FTOT, 256, 0, stream>>>(W0, Wt);
    wct_pack<<<NC, 256, 0, stream>>>(Wc, Wct);

    gemm_h<<<dim3(NPAD / 128, FTOT / 128), 256, 0, stream>>>(Xbf, Wt, Ht);
    f12_kern<<<dim3((NPAD + 255) / 256, NH), 256, 0, stream>>>(Ht, a10, a20, f1, f2, HID);
    rarb_kern<<<NH, 256, 0, stream>>>(f1, f2, RA, RB, E2F, E2Fb);

    attn_main<<<dim3(47 * 2 * NH), 256, 0, stream>>>(Ht, mask, RA, RB, E2F, E2Fb, x2);

    gemm_hc<<<dim3(NPAD / 128, 8), 256, 0, stream>>>(Wct, x2, pkhc);
    merge_hc<<<dim3((NPAD + 255) / 256, NC), 256, 0, stream>>>(pkhc, hct);
    f12_kern<<<dim3((NPAD + 255) / 256, 1), 256, 0, stream>>>(hct, a1c, a2c, f1c, f2c, NC);
    rarb_kern<<<1, 256, 0, stream>>>(f1c, f2c, RAc, RBc, E2Fc, E2Fcb);

    cls_part<<<dim3(47, 8), 256, 0, stream>>>(hct, mask, RAc, RBc, E2Fc, E2Fcb, pacc, pdsum);
    cls_merge<<<750, 256, 0, stream>>>(pacc, pdsum, out);
}

// Round 15
// 427.364 us; speedup vs baseline: 1.7687x; 1.0499x over previous
//
#include <hip/hip_runtime.h>
#include <hip/hip_bf16.h>

#define NN 6000
#define NPAD 6016      // 94*64
#define DF 512
#define HID 256
#define NH 8
#define NC 32
#define FTOT 2048
#define MSTR 96        // u64 words per mask row
#define NJB (NPAD / 64)
#define NJT (NPAD / 32)
#define L2E 1.4426950408889634f

using short8 = __attribute__((ext_vector_type(8))) short;
using f32x16 = __attribute__((ext_vector_type(16))) float;
using f32x4  = __attribute__((ext_vector_type(4))) float;

__device__ __forceinline__ unsigned short f2bf(float f) {
    unsigned int u = __float_as_uint(f);
    return (unsigned short)((u + 0x7fffu + ((u >> 16) & 1u)) >> 16);
}
__device__ __forceinline__ float bf2f(unsigned short s) {
    return __uint_as_float(((unsigned int)s) << 16);
}
// async global->LDS, 16B per lane
__device__ __forceinline__ void gl16(const void* g, void* l) {
    __builtin_amdgcn_global_load_lds(
        (const __attribute__((address_space(1))) unsigned int*)g,
        (__attribute__((address_space(3))) unsigned int*)l, 16, 0, 0);
}

// ---------------- prep kernels (verified r3/r4) ----------------

__global__ void pack_bits(const int* __restrict__ adj, unsigned char* __restrict__ maskb) {
    int row = blockIdx.y;
    int b = blockIdx.x * 256 + threadIdx.x;     // byte index 0..767
    if (b >= 768) return;
    int j0 = b * 8;
    unsigned int v = 0;
    if (j0 + 7 < NN) {
        const int4* p = (const int4*)(adj + (size_t)row * NN + j0);
        int4 a = p[0], c = p[1];
        v = (unsigned)((a.x>0) | ((a.y>0)<<1) | ((a.z>0)<<2) | ((a.w>0)<<3)
          | ((c.x>0)<<4) | ((c.y>0)<<5) | ((c.z>0)<<6) | ((c.w>0)<<7));
    }
    maskb[(size_t)row * 768 + b] = (unsigned char)v;
}

__global__ void cast_x4(const float* __restrict__ x, unsigned short* __restrict__ xb, int n4) {
    int i = blockIdx.x * 256 + threadIdx.x;
    if (i >= n4) return;
    float4 v = ((const float4*)x)[i];
    unsigned long long pk = (unsigned long long)f2bf(v.x)
        | ((unsigned long long)f2bf(v.y) << 16)
        | ((unsigned long long)f2bf(v.z) << 32)
        | ((unsigned long long)f2bf(v.w) << 48);
    ((unsigned long long*)xb)[i] = pk;
}

__global__ void wt_pack(const float* __restrict__ W0, unsigned short* __restrict__ Wt) {
    int fp = blockIdx.x;                 // h*256+f
    int h = fp >> 8, f = fp & 255;
    for (int k = threadIdx.x; k < DF; k += 256)
        Wt[(size_t)fp * DF + k] = f2bf(W0[(((size_t)h * DF + k) << 8) | f]);
}

__global__ void wct_pack(const float* __restrict__ Wc, unsigned short* __restrict__ Wct) {
    int c = blockIdx.x;
    for (int k = threadIdx.x; k < FTOT; k += 256)
        Wct[(size_t)c * FTOT + k] = f2bf(Wc[(size_t)k * NC + c]);
}

// ---------------- GEMM1 (verified r3): Ht[f][i] = sum_k X[i][k] W[k][f] ----------------
__global__ __launch_bounds__(256, 2) void gemm_h(const unsigned short* __restrict__ A,
                                                 const unsigned short* __restrict__ B,
                                                 unsigned short* __restrict__ Ht) {
    __shared__ __align__(16) unsigned short As[128 * 64];
    __shared__ __align__(16) unsigned short Bs[128 * 64];
    const int w = threadIdx.x >> 6, l = threadIdx.x & 63;
    const int lrow = l & 31, kh = l >> 5;
    const int wm = w >> 1, wn = w & 1;
    const int mbase = blockIdx.x * 128, nbase = blockIdx.y * 128;
    const int srcc = (l & 7) ^ (l >> 3);
    f32x16 acc[2][2];
#pragma unroll
    for (int i = 0; i < 2; ++i)
#pragma unroll
        for (int j = 0; j < 2; ++j) acc[i][j] = (f32x16)0.0f;

#pragma unroll 1
    for (int kb = 0; kb < DF / 64; ++kb) {
        __syncthreads();
#pragma unroll
        for (int q = 0; q < 4; ++q) {
            int c = q * 4 + w;
            int r = c * 8 + (l >> 3);
            int arow = mbase + r; if (arow > NN - 1) arow = NN - 1;
            gl16(A + (size_t)arow * DF + kb * 64 + srcc * 8, (char*)As + c * 1024);
            gl16(B + (size_t)(nbase + r) * DF + kb * 64 + srcc * 8, (char*)Bs + c * 1024);
        }
        __syncthreads();
#pragma unroll
        for (int kk = 0; kk < 4; ++kk) {
            short8 av[2], bv[2];
#pragma unroll
            for (int mt = 0; mt < 2; ++mt) {
                int r = wm * 64 + mt * 32 + lrow;
                av[mt] = *(const short8*)((const char*)As + r * 128 + ((((kk << 1) | kh) ^ (r & 7)) << 4));
            }
#pragma unroll
            for (int ft = 0; ft < 2; ++ft) {
                int r = wn * 64 + ft * 32 + lrow;
                bv[ft] = *(const short8*)((const char*)Bs + r * 128 + ((((kk << 1) | kh) ^ (r & 7)) << 4));
            }
#pragma unroll
            for (int mt = 0; mt < 2; ++mt)
#pragma unroll
                for (int ft = 0; ft < 2; ++ft)
                    acc[mt][ft] = __builtin_amdgcn_mfma_f32_32x32x16_bf16(av[mt], bv[ft], acc[mt][ft], 0, 0, 0);
        }
    }
#pragma unroll
    for (int mt = 0; mt < 2; ++mt)
#pragma unroll
        for (int ft = 0; ft < 2; ++ft) {
            size_t n = nbase + wn * 64 + ft * 32 + lrow;
#pragma unroll
            for (int g = 0; g < 4; ++g) {
                int m0 = mbase + wm * 64 + mt * 32 + (g << 3) + (kh << 2);
                unsigned long long pk =
                    (unsigned long long)f2bf(acc[mt][ft][g * 4 + 0]) |
                    ((unsigned long long)f2bf(acc[mt][ft][g * 4 + 1]) << 16) |
                    ((unsigned long long)f2bf(acc[mt][ft][g * 4 + 2]) << 32) |
                    ((unsigned long long)f2bf(acc[mt][ft][g * 4 + 3]) << 48);
                *(unsigned long long*)(Ht + n * NPAD + m0) = pk;
            }
        }
}

// ---------------- f1/f2, pre-scaled by log2e (verified r6) ----------------
__global__ void f12_kern(const unsigned short* __restrict__ Ht, const float* __restrict__ a1,
                         const float* __restrict__ a2, float* __restrict__ f1, float* __restrict__ f2,
                         int fdim) {
    int h = blockIdx.y;
    int i = blockIdx.x * 256 + threadIdx.x;
    if (i >= NPAD) return;
    float s1 = 0.f, s2 = 0.f;
    const unsigned short* base = Ht + (size_t)h * fdim * NPAD + i;
    for (int f = 0; f < fdim; ++f) {
        float v = bf2f(base[(size_t)f * NPAD]);
        s1 = fmaf(v, a1[h * fdim + f], s1);
        s2 = fmaf(v, a2[h * fdim + f], s2);
    }
    f1[(size_t)h * NPAD + i] = s1 * L2E;
    f2[(size_t)h * NPAD + i] = s2 * L2E;
}

// per-head global max -> RA/RB + E2F/E2Fb (verified r14)
__global__ void rarb_kern(const float* __restrict__ f1all, const float* __restrict__ f2all,
                          float* __restrict__ RA, float* __restrict__ RB,
                          float* __restrict__ E2F, float* __restrict__ E2Fb) {
    int h = blockIdx.x;
    __shared__ float red[8];
    const float* f2h = f2all + (size_t)h * NPAD;
    float m = -3.0e38f;
    for (int i = threadIdx.x; i < NN; i += 256) m = fmaxf(m, f2h[i]);
    for (int off = 32; off; off >>= 1) m = fmaxf(m, __shfl_xor(m, off));
    if ((threadIdx.x & 63) == 0) red[threadIdx.x >> 6] = m;
    __syncthreads();
    if (threadIdx.x == 0)
        red[4] = fmaxf(fmaxf(red[0], red[1]), fmaxf(red[2], red[3]));
    __syncthreads();
    float Mh = red[4];
    for (int i = threadIdx.x; i < NPAD; i += 256) {
        float F1 = (i < NN) ? f1all[(size_t)h * NPAD + i] : 0.f;
        float t2 = F1 + Mh;
        float Mi = fmaxf(t2, 0.2f * t2);
        RA[(size_t)h * NPAD + i] = F1 - Mi;
        RB[(size_t)h * NPAD + i] = 0.2f * F1 - Mi;
        float v2 = f2h[i];
        E2F[(size_t)h * NPAD + i] = exp2f(v2);
        E2Fb[(size_t)h * NPAD + i] = exp2f(0.2f * v2);
    }
}

// ---------------- main attention v10: 16x16x32 MFMA, full-F per block, NO P duplication ----------------
// grid 752: h = bid&7 (head->XCD pin), rowblk = bid>>3 (64 rows, 4 waves x 16).
// Tile [256 f][32 j] = 16 KB, triple-buffered (48 KB). r8-verified loop:
//   STAGE(t+1) (4 gl16/wave) -> vmcnt(4) -> s_barrier -> compute(t).
// Per tile per wave: ONE A-frag (P for 16 rows x 32 j, computed once chip-wide) + 17 MFMA.
// 16x16x32 layouts (m89-verified): A row = l&15, k=(l>>4)*8+e; D col = l&15, row=(l>>4)*4+t.
// ones-trick dsum -> asum4[t] is the rowsum for D-row (l>>4)*4+t (per-lane, no shuffles).
__global__ __launch_bounds__(256, 3) void attn_main(
    const unsigned short* __restrict__ Ht,
    const unsigned long long* __restrict__ mask,
    const float* __restrict__ RA, const float* __restrict__ RB,
    const float* __restrict__ E2F, const float* __restrict__ E2Fb,
    unsigned short* __restrict__ x2)
{
    __shared__ __align__(16) unsigned short htile[3 * 256 * 32];   // 48 KB: 3 x [256 f][32 j]
    const int bid = blockIdx.x;
    const int h = bid & 7;
    const int rowbase = (bid >> 3) * 64;
    const int w = threadIdx.x >> 6, l = threadIdx.x & 63;
    const int la = l & 15;            // A row within wave's 16-row group
    const int s  = l >> 4;            // k-group (8 j's)
    const int rowA = rowbase + w * 16 + la;
    const int rowAc = (rowA < NN) ? rowA : NN - 1;
    const unsigned short* Hh = Ht + (size_t)h * HID * NPAD;
    const float* E2Fh = E2F + (size_t)h * NPAD;
    const float* E2Fbh = E2Fb + (size_t)h * NPAD;
    const float era = exp2f(RA[(size_t)h * NPAD + rowAc]);
    const float erb = exp2f(RB[(size_t)h * NPAD + rowAc]);
    const short8 ones = { (short)0x3F80, (short)0x3F80, (short)0x3F80, (short)0x3F80,
                          (short)0x3F80, (short)0x3F80, (short)0x3F80, (short)0x3F80 };
    f32x4 acc16[16];
    f32x4 asum4 = (f32x4)0.0f;
#pragma unroll
    for (int i = 0; i < 16; ++i) acc16[i] = (f32x4)0.0f;

    // staging: chunk c (0..15) = rows c*16..c*16+15; lane l -> row c*16+(l>>2), stored seg l&3.
    // source pre-swizzle: fetch seg (l&3)^(row&3) so read-side XOR seg^(f&3) lands right (rule #21).
    const int segsrc = (l & 3) ^ ((l >> 2) & 3);
    auto STAGE = [&](int buf, int jt) {
#pragma unroll
        for (int q = 0; q < 4; ++q) {
            int c = q * 4 + w;                       // chunk 0..15
            int f = c * 16 + (l >> 2);               // feature row 0..255
            gl16(Hh + (size_t)f * NPAD + jt * 32 + segsrc * 8,
                 (char*)htile + buf * 16384 + c * 1024);
        }
    };

    STAGE(0, 0);
#pragma unroll 1
    for (int jt = 0; jt < NJT; ++jt) {
        if (jt + 1 < NJT) STAGE((jt + 1) % 3, jt + 1);     // depth-1 prefetch (4 gl16, static)
        asm volatile("s_waitcnt vmcnt(4)" ::: "memory");   // own S(jt) retired; prefetch in flight
        __builtin_amdgcn_sched_barrier(0);
        __builtin_amdgcn_s_barrier();                      // publish tile jt (non-draining)
        __builtin_amdgcn_sched_barrier(0);
        const char* tb = (const char*)htile + (jt % 3) * 16384;
        unsigned int mwrd = ((const unsigned int*)mask)[(size_t)rowAc * 192 + jt];
        unsigned int mbyte = (mwrd >> (s * 8)) & 0xffu;
        int j0 = jt * 32 + s * 8;
        f32x4 ea0 = *(const f32x4*)(E2Fh + j0);
        f32x4 ea1 = *(const f32x4*)(E2Fh + j0 + 4);
        f32x4 eb0 = *(const f32x4*)(E2Fbh + j0);
        f32x4 eb1 = *(const f32x4*)(E2Fbh + j0 + 4);
        float p[8];
#pragma unroll
        for (int e = 0; e < 8; ++e) {
            float fe = (e < 4) ? ea0[e & 3] : ea1[e & 3];
            float fb = (e < 4) ? eb0[e & 3] : eb1[e & 3];
            float pe = fmaxf(era * fe, erb * fb);          // == exp2(max(ra+f, rb+0.2f))
            p[e] = (mbyte & (1u << e)) ? pe : 0.f;
        }
        union { unsigned int u[4]; short8 s8; } cv;
#pragma unroll
        for (int q = 0; q < 4; ++q)
            cv.u[q] = __builtin_amdgcn_perm(__float_as_uint(p[2 * q + 1]),
                                            __float_as_uint(p[2 * q]), 0x07060302u);
        __builtin_amdgcn_s_setprio(1);
        asum4 = __builtin_amdgcn_mfma_f32_16x16x32_bf16(cv.s8, ones, asum4, 0, 0, 0);
#pragma unroll
        for (int ft = 0; ft < 16; ++ft) {
            int fl = ft * 16 + la;                          // B col = feature row in tile
            int slot = s ^ (fl & 3);
            short8 bfrag = *(const short8*)(tb + fl * 64 + slot * 16);
            acc16[ft] = __builtin_amdgcn_mfma_f32_16x16x32_bf16(cv.s8, bfrag, acc16[ft], 0, 0, 0);
        }
        __builtin_amdgcn_s_setprio(0);
    }

    // D row = (l>>4)*4 + t; asum4[t] = that row's denominator (ones-trick, per-lane)
    float dinv[4];
#pragma unroll
    for (int t = 0; t < 4; ++t)
        dinv[t] = (asum4[t] > 0.f) ? (1.0f / asum4[t]) : 0.f;

#pragma unroll
    for (int ft = 0; ft < 16; ++ft)
#pragma unroll
        for (int t = 0; t < 4; ++t) {
            int grow = rowbase + w * 16 + s * 4 + t;
            if (grow < NN) {
                float v = acc16[ft][t] * dinv[t];
                v = (v > 0.f) ? v : (__expf(v) - 1.f);
                x2[(size_t)grow * FTOT + h * HID + ft * 16 + la] = f2bf(v);
            }
        }
}

// ---------------- GEMM2: split-K x8 -> f32 partials (verified r5) ----------------
__global__ __launch_bounds__(256, 2) void gemm_hc(const unsigned short* __restrict__ A,
                                                  const unsigned short* __restrict__ B,
                                                  float* __restrict__ pk) {
    int w = threadIdx.x >> 6, l = threadIdx.x & 63;
    int lrow = l & 31, kh = l >> 5;
    int q = blockIdx.y;
    int nbase = blockIdx.x * 128 + w * 32;
    int brow = nbase + lrow; if (brow > NN - 1) brow = NN - 1;
    f32x16 acc = (f32x16)0.0f;
    const short8* ap = (const short8*)(A + (size_t)lrow * FTOT + q * 256 + kh * 8);
    const short8* bp = (const short8*)(B + (size_t)brow * FTOT + q * 256 + kh * 8);
#pragma unroll
    for (int kk = 0; kk < 16; ++kk) {
        short8 af = ap[kk * 2];
        short8 bf = bp[kk * 2];
        acc = __builtin_amdgcn_mfma_f32_32x32x16_bf16(af, bf, acc, 0, 0, 0);
    }
    int i = nbase + lrow;
#pragma unroll
    for (int g = 0; g < 4; ++g) {
        int c0 = (g << 3) + (kh << 2);
#pragma unroll
        for (int r = 0; r < 4; ++r)
            pk[((size_t)q * NC + c0 + r) * NPAD + i] = acc[g * 4 + r];
    }
}

__global__ void merge_hc(const float* __restrict__ pk, unsigned short* __restrict__ hct) {
    int i = blockIdx.x * 256 + threadIdx.x;
    int c = blockIdx.y;
    if (i >= NPAD) return;
    float s = 0.f;
#pragma unroll
    for (int q = 0; q < 8; ++q) s += pk[((size_t)q * NC + c) * NPAD + i];
    hct[(size_t)c * NPAD + i] = f2bf(s);
}

// ---------------- classifier attention (verified r14): barrier-free, j-split 8, ones dsum ----------------
__global__ __launch_bounds__(256) void cls_part(
    const unsigned short* __restrict__ hctb,
    const unsigned long long* __restrict__ mask,
    const float* __restrict__ RAc, const float* __restrict__ RBc,
    const float* __restrict__ E2Fc, const float* __restrict__ E2Fcb,
    float* __restrict__ pacc, float* __restrict__ pdsum)
{
    const int w = threadIdx.x >> 6, l = threadIdx.x & 63;
    const int lrow = l & 31, kh = l >> 5;
    const int q = blockIdx.y;
    const int rowbase = blockIdx.x * 128;
    const int myrow = rowbase + w * 32 + lrow;
    const bool act = myrow < NN;
    const float era = exp2f(RAc[myrow]);
    const float erb = exp2f(RBc[myrow]);
    const int JB0 = q * 12, JB1 = (JB0 + 12 < NJB) ? JB0 + 12 : NJB;
    const short8 ones = { (short)0x3F80, (short)0x3F80, (short)0x3F80, (short)0x3F80,
                          (short)0x3F80, (short)0x3F80, (short)0x3F80, (short)0x3F80 };
    f32x16 acc = (f32x16)0.0f;
    f32x16 asum = (f32x16)0.0f;

#pragma unroll 1
    for (int jb = JB0; jb < JB1; ++jb) {
        unsigned long long mword = act ? mask[(size_t)myrow * MSTR + jb] : 0ull;
#pragma unroll
        for (int kk = 0; kk < 4; ++kk) {
            short8 bfrag = *(const short8*)(hctb + (size_t)lrow * NPAD + jb * 64 + (kk * 2 + kh) * 8);
            unsigned int mbyte = (unsigned int)((mword >> (kk * 16 + kh * 8)) & 0xffull);
            int j0 = jb * 64 + kk * 16 + kh * 8;
            f32x4 ea0 = *(const f32x4*)(E2Fc + j0);
            f32x4 ea1 = *(const f32x4*)(E2Fc + j0 + 4);
            f32x4 eb0 = *(const f32x4*)(E2Fcb + j0);
            f32x4 eb1 = *(const f32x4*)(E2Fcb + j0 + 4);
            float p[8];
#pragma unroll
            for (int e = 0; e < 8; ++e) {
                float fe = (e < 4) ? ea0[e & 3] : ea1[e & 3];
                float fb = (e < 4) ? eb0[e & 3] : eb1[e & 3];
                float pe = fmaxf(era * fe, erb * fb);
                p[e] = (mbyte & (1u << e)) ? pe : 0.f;
            }
            union { unsigned int u[4]; short8 s8; } cv;
#pragma unroll
            for (int t = 0; t < 4; ++t)
                cv.u[t] = __builtin_amdgcn_perm(__float_as_uint(p[2 * t + 1]),
                                                __float_as_uint(p[2 * t]), 0x07060302u);
            asum = __builtin_amdgcn_mfma_f32_32x32x16_bf16(cv.s8, ones, asum, 0, 0, 0);
            acc = __builtin_amdgcn_mfma_f32_32x32x16_bf16(cv.s8, bfrag, acc, 0, 0, 0);
        }
    }
#pragma unroll
    for (int g = 0; g < 4; ++g)
#pragma unroll
        for (int rr = 0; rr < 4; ++rr) {
            int i = rowbase + w * 32 + (g << 3) + (kh << 2) + rr;
            pacc[((size_t)q * NPAD + i) * NC + lrow] = acc[g * 4 + rr];
            if (lrow == 0) pdsum[(size_t)q * NPAD + i] = asum[g * 4 + rr];
        }
}

__global__ void cls_merge(const float* __restrict__ pacc, const float* __restrict__ pdsum,
                          float* __restrict__ outp) {
    int i = blockIdx.x * 8 + (threadIdx.x >> 5);
    int c = threadIdx.x & 31;
    if (i >= NN) return;
    float num = 0.f, den = 0.f;
#pragma unroll
    for (int q = 0; q < 8; ++q) {
        num += pacc[((size_t)q * NPAD + i) * NC + c];
        den += pdsum[(size_t)q * NPAD + i];
    }
    outp[(size_t)i * NC + c] = (den > 0.f) ? num / den : 0.f;
}

// ---------------- launcher ----------------
extern "C" void kernel_launch(void* const* d_in, const int* in_sizes, int n_in,
                              void* d_out, int out_size, void* d_ws, size_t ws_size,
                              hipStream_t stream) {
    const float* features = (const float*)d_in[0];
    const int*   adj      = (const int*)d_in[1];
    const float* W0       = (const float*)d_in[2];
    const float* a10      = (const float*)d_in[3];
    const float* a20      = (const float*)d_in[4];
    const float* Wc       = (const float*)d_in[5];
    const float* a1c      = (const float*)d_in[6];
    const float* a2c      = (const float*)d_in[7];
    float* out = (float*)d_out;

    char* p = (char*)d_ws;
    auto alloc = [&](size_t bytes) { char* r = p; p += (bytes + 255) & ~(size_t)255; return r; };
    unsigned long long* mask = (unsigned long long*)alloc((size_t)NN * MSTR * 8);
    unsigned short* Xbf = (unsigned short*)alloc((size_t)NN * DF * 2);
    unsigned short* Wt  = (unsigned short*)alloc((size_t)FTOT * DF * 2);
    unsigned short* Ht  = (unsigned short*)alloc((size_t)FTOT * NPAD * 2);
    unsigned short* x2  = (unsigned short*)alloc((size_t)NN * FTOT * 2);
    unsigned short* Wct = (unsigned short*)alloc((size_t)NC * FTOT * 2);
    unsigned short* hct = (unsigned short*)alloc((size_t)NC * NPAD * 2);
    float* f1  = (float*)alloc((size_t)NH * NPAD * 4);
    float* f2  = (float*)alloc((size_t)NH * NPAD * 4);
    float* RA  = (float*)alloc((size_t)NH * NPAD * 4);
    float* RB  = (float*)alloc((size_t)NH * NPAD * 4);
    float* E2F  = (float*)alloc((size_t)NH * NPAD * 4);
    float* E2Fb = (float*)alloc((size_t)NH * NPAD * 4);
    float* f1c  = (float*)alloc((size_t)NPAD * 4);
    float* f2c  = (float*)alloc((size_t)NPAD * 4);
    float* RAc  = (float*)alloc((size_t)NPAD * 4);
    float* RBc  = (float*)alloc((size_t)NPAD * 4);
    float* E2Fc  = (float*)alloc((size_t)NPAD * 4);
    float* E2Fcb = (float*)alloc((size_t)NPAD * 4);
    // overlays on dead Xbf+Wt (8.26 MB): pkhc 6.16 MB (gemm_hc), then pacc 6.16 MB + pdsum 192 KB (cls)
    float* pkhc  = (float*)Xbf;
    float* pacc  = (float*)Xbf;
    float* pdsum = pacc + (size_t)8 * NPAD * NC;

    pack_bits<<<dim3(3, NN), 256, 0, stream>>>(adj, (unsigned char*)mask);
    cast_x4<<<(NN * DF / 4 + 255) / 256, 256, 0, stream>>>(features, Xbf, NN * DF / 4);
    wt_pack<<<FTOT, 256, 0, stream>>>(W0, Wt);
    wct_pack<<<NC, 256, 0, stream>>>(Wc, Wct);

    gemm_h<<<dim3(NPAD / 128, FTOT / 128), 256, 0, stream>>>(Xbf, Wt, Ht);
    f12_kern<<<dim3((NPAD + 255) / 256, NH), 256, 0, stream>>>(Ht, a10, a20, f1, f2, HID);
    rarb_kern<<<NH, 256, 0, stream>>>(f1, f2, RA, RB, E2F, E2Fb);

    attn_main<<<dim3(94 * NH), 256, 0, stream>>>(Ht, mask, RA, RB, E2F, E2Fb, x2);

    gemm_hc<<<dim3(NPAD / 128, 8), 256, 0, stream>>>(Wct, x2, pkhc);
    merge_hc<<<dim3((NPAD + 255) / 256, NC), 256, 0, stream>>>(pkhc, hct);
    f12_kern<<<dim3((NPAD + 255) / 256, 1), 256, 0, stream>>>(hct, a1c, a2c, f1c, f2c, NC);
    rarb_kern<<<1, 256, 0, stream>>>(f1c, f2c, RAc, RBc, E2Fc, E2Fcb);

    cls_part<<<dim3(47, 8), 256, 0, stream>>>(hct, mask, RAc, RBc, E2Fc, E2Fcb, pacc, pdsum);
    cls_merge<<<750, 256, 0, stream>>>(pacc, pdsum, out);
}